// Round 3
// baseline (1137.203 us; speedup 1.0000x reference)
//
#include <hip/hip_runtime.h>
#include <hip/hip_bf16.h>

typedef __hip_bfloat16 bf16;

#define NROI 200

__device__ __forceinline__ float u2f(unsigned short u) {
  return __uint_as_float(((unsigned)u) << 16);
}
__device__ __forceinline__ float b2f(bf16 v) { return __bfloat162float(v); }

__device__ __forceinline__ float mishf(float x) {
  float sp = (x > 20.0f) ? x : log1pf(expf(x));
  return x * tanhf(sp);
}

// ---------------- dtype detection ----------------
// flags[0]=1 if float tensors are f32 (else bf16); flags[1]=1 if edge_index is int64.
__global__ __launch_bounds__(256) void detect_kernel(const unsigned short* xu,
                                                     const unsigned* eiw,
                                                     int* flags) {
  int tid = threadIdx.x;
  int sane = 0, zodd = 0;
  for (int i = tid; i < 4096; i += 256) {
    unsigned short u = xu[2 * i];          // even bf16 slots: real values iff x is bf16
    unsigned e = (u >> 7) & 0xFF;
    if (u == 0 || (e >= 100 && e <= 134)) sane++;
  }
  for (int i = tid; i < 4096; i += 256) {
    if (eiw[2 * i + 1] == 0) zodd++;       // high words zero iff int64
  }
  __shared__ int s1[256], s2[256];
  s1[tid] = sane; s2[tid] = zodd;
  __syncthreads();
  for (int off = 128; off > 0; off >>= 1) {
    if (tid < off) { s1[tid] += s1[tid + off]; s2[tid] += s2[tid + off]; }
    __syncthreads();
  }
  if (tid == 0) {
    flags[0] = (s1[0] < 2048) ? 1 : 0;
    flags[1] = (s2[0] > 2048) ? 1 : 0;
  }
}

// ---------------- weight canonicalization (-> bf16) ----------------
struct WArgs {
  const void* src[16];
  int n[16];
  int off[16];
};

__global__ __launch_bounds__(256) void convert_weights(WArgs a, bf16* base,
                                                       const int* flags) {
  int t = blockIdx.y;
  int i = blockIdx.x * 256 + threadIdx.x;
  if (i >= a.n[t]) return;
  bf16* dst = base + a.off[t];
  if (flags[0]) dst[i] = __float2bfloat16(((const float*)a.src[t])[i]);
  else ((unsigned short*)dst)[i] = ((const unsigned short*)a.src[t])[i];
}

// ---------------- graph preprocessing ----------------

__global__ void init_deg_cnt(float* deg, int* cnt, int N) {
  int i = blockIdx.x * blockDim.x + threadIdx.x;
  if (i < N) { deg[i] = 1.0f; cnt[i] = 0; }   // self-loop weight 1
}

__global__ void edge_count(const int* __restrict__ ei, const void* __restrict__ ea,
                           const int* __restrict__ flags,
                           float* deg, int* cnt, int E) {
  int e = blockIdx.x * blockDim.x + threadIdx.x;
  if (e >= E) return;
  int is64 = flags[1], isf32 = flags[0];
  int col = is64 ? ei[2 * (E + e)] : ei[E + e];
  float w = isf32 ? ((const float*)ea)[e] : u2f(((const unsigned short*)ea)[e]);
  atomicAdd(&deg[col], w);
  atomicAdd(&cnt[col], 1);
}

__global__ void make_dis(float* deg, int N) {
  int i = blockIdx.x * blockDim.x + threadIdx.x;
  if (i < N) deg[i] = rsqrtf(deg[i]);   // deg >= 1 always (self-loop)
}

__global__ __launch_bounds__(1024) void prefix_kernel(const int* __restrict__ cnt,
                                                      int* ptr, int* pos, int N) {
  __shared__ int pA[1024];
  __shared__ int pB[1024];
  int tid = threadIdx.x;
  int chunk = (N + 1023) / 1024;
  int start = tid * chunk;
  int end = start + chunk; if (end > N) end = N; if (start > N) start = N;
  int s = 0;
  for (int i = start; i < end; ++i) s += cnt[i];
  pA[tid] = s;
  __syncthreads();
  int* src = pA; int* dst = pB;
  for (int off = 1; off < 1024; off <<= 1) {
    int v = src[tid];
    if (tid >= off) v += src[tid - off];
    dst[tid] = v;
    __syncthreads();
    int* tmp = src; src = dst; dst = tmp;
  }
  int run = (tid == 0) ? 0 : src[tid - 1];
  for (int i = start; i < end; ++i) {
    ptr[i] = run; pos[i] = run; run += cnt[i];
  }
  if (tid == 1023) ptr[N] = run;
}

__global__ void edge_scatter(const int* __restrict__ ei, const void* __restrict__ ea,
                             const int* __restrict__ flags,
                             const float* __restrict__ dis, int* pos,
                             int* erow, float* enorm, int E) {
  int e = blockIdx.x * blockDim.x + threadIdx.x;
  if (e >= E) return;
  int is64 = flags[1], isf32 = flags[0];
  int r = is64 ? ei[2 * e] : ei[e];
  int c = is64 ? ei[2 * (E + e)] : ei[E + e];
  float w = isf32 ? ((const float*)ea)[e] : u2f(((const unsigned short*)ea)[e]);
  float nrm = dis[r] * w * dis[c];
  int idx = atomicAdd(&pos[c], 1);
  erow[idx] = r;
  enorm[idx] = nrm;
}

// ---------------- dense compute ----------------

// H[M,NC] = A[M,K] @ W[K,NC]   (W bf16 in LDS; f32 accum; H stored bf16)
template<int K, int NC, int RPC>
__global__ __launch_bounds__(256) void gemm_kernel(const void* __restrict__ A,
                                                   const bf16* __restrict__ W,
                                                   bf16* __restrict__ H,
                                                   const int* __restrict__ flags,
                                                   int force_f32) {
  constexpr int RPB = 64;
  constexpr int NT  = 256;
  static_assert(RPC * NC == NT, "bad shape");
  __shared__ unsigned short Ws[K * NC];
  __shared__ float As[RPC * K];
  int tid = threadIdx.x;
  int isf32 = force_f32 ? 1 : flags[0];
  const unsigned short* Wu = (const unsigned short*)W;
  for (int i = tid; i < K * NC; i += NT) Ws[i] = Wu[i];
  const float* Af = (const float*)A;
  const unsigned short* Au = (const unsigned short*)A;
  int tx = tid % NC, ty = tid / NC;
  size_t row0 = (size_t)blockIdx.x * RPB;
  for (int r = 0; r < RPB; r += RPC) {
    __syncthreads();
    for (int i = tid; i < RPC * K; i += NT) {
      int rr = i / K, kk = i - rr * K;
      size_t off = (row0 + r + rr) * K + kk;
      As[i] = isf32 ? Af[off] : u2f(Au[off]);
    }
    __syncthreads();
    float acc = 0.0f;
#pragma unroll 8
    for (int k = 0; k < K; ++k) {
      acc += As[ty * K + k] * u2f(Ws[k * NC + tx]);
    }
    H[(row0 + r + ty) * NC + tx] = __float2bfloat16(acc);
  }
}

// g[n,f] = mish( sum_{e in CSR[n]} h[row_e,f]*norm_e + h[n,f]*dis[n]^2 + bias[f] )
template<int F>
__global__ __launch_bounds__(256) void agg_mish(const bf16* __restrict__ h,
                                                const float* __restrict__ dis,
                                                const int* __restrict__ ptr,
                                                const int* __restrict__ erow,
                                                const float* __restrict__ enorm,
                                                const bf16* __restrict__ bias,
                                                float* __restrict__ g, int N) {
  constexpr int NPB = 256 / F;
  int n = blockIdx.x * NPB + threadIdx.x / F;
  int f = threadIdx.x % F;
  if (n >= N) return;
  float dn = dis[n];
  float acc = b2f(h[(size_t)n * F + f]) * dn * dn;   // self-loop
  int e0 = ptr[n], e1 = ptr[n + 1];
  for (int e = e0; e < e1; ++e)
    acc += b2f(h[(size_t)erow[e] * F + f]) * enorm[e];
  g[(size_t)n * F + f] = mishf(acc + b2f(bias[f]));
}

// out8[n,c] = mish(g2[n,:64] @ Wro[:,c] + bro[c])
__global__ __launch_bounds__(256) void ro_kernel(const float* __restrict__ g2,
                                                 const bf16* __restrict__ Wro,
                                                 const bf16* __restrict__ bro,
                                                 float* __restrict__ out8, int N) {
  int idx = blockIdx.x * 256 + threadIdx.x;
  if (idx >= N * 8) return;
  int n = idx >> 3, c = idx & 7;
  float acc = b2f(bro[c]);
#pragma unroll 8
  for (int k = 0; k < 64; ++k) acc += g2[(size_t)n * 64 + k] * b2f(Wro[k * 8 + c]);
  out8[idx] = mishf(acc);
}

// z[b,j] = feat[b,:1600] @ Wfc1[:,j] + bfc1[j]
__global__ __launch_bounds__(256) void fc1_kernel(const float* __restrict__ feat,
                                                  const bf16* __restrict__ W,
                                                  const bf16* __restrict__ bias,
                                                  float* __restrict__ z) {
  __shared__ float fr[1600];
  int b = blockIdx.x, tid = threadIdx.x;
  for (int i = tid; i < 1600; i += 256) fr[i] = feat[(size_t)b * 1600 + i];
  __syncthreads();
  if (tid < NROI) {
    float acc = b2f(bias[tid]);
#pragma unroll 8
    for (int k = 0; k < 1600; ++k) acc += fr[k] * b2f(W[k * NROI + tid]);
    z[b * NROI + tid] = acc;
  }
}

__global__ __launch_bounds__(256) void bn_stats(const float* __restrict__ z,
                                                float* mu, float* rvar, int B) {
  int j = blockIdx.x;
  int tid = threadIdx.x;
  float v = z[tid * NROI + j];
  float s = v, q = v * v;
  for (int off = 32; off > 0; off >>= 1) {
    s += __shfl_down(s, off);
    q += __shfl_down(q, off);
  }
  __shared__ float ss[4], qq[4];
  int w = tid >> 6, lane = tid & 63;
  if (lane == 0) { ss[w] = s; qq[w] = q; }
  __syncthreads();
  if (tid == 0) {
    float S = ss[0] + ss[1] + ss[2] + ss[3];
    float Q = qq[0] + qq[1] + qq[2] + qq[3];
    float m = S / (float)B;
    float var = Q / (float)B - m * m;
    mu[j] = m;
    rvar[j] = rsqrtf(var + 1e-5f);
  }
}

__global__ __launch_bounds__(256) void head_kernel(const float* __restrict__ z,
                                                   const float* __restrict__ mu,
                                                   const float* __restrict__ rvar,
                                                   const bf16* __restrict__ gamma,
                                                   const bf16* __restrict__ beta,
                                                   const bf16* __restrict__ Wfc2,
                                                   const bf16* __restrict__ bfc2,
                                                   const bf16* __restrict__ Wd1,
                                                   const bf16* __restrict__ bd1,
                                                   const bf16* __restrict__ Wd2,
                                                   const bf16* __restrict__ bd2,
                                                   float* __restrict__ out, int B) {
  __shared__ float mid[NROI];
  __shared__ float t[64];
  int b = blockIdx.x, tid = threadIdx.x;
  if (tid < NROI) {
    float v = (z[b * NROI + tid] - mu[tid]) * rvar[tid] * b2f(gamma[tid]) + b2f(beta[tid]);
    mid[tid] = mishf(v);
  }
  __syncthreads();
  if (tid < 64) {
    float acc = b2f(bd1[tid]);
#pragma unroll 8
    for (int j = 0; j < NROI; ++j) acc += mid[j] * b2f(Wd1[j * 64 + tid]);
    t[tid] = fmaxf(acc, 0.0f);
  }
  if (tid >= 64 && tid < 66) {
    int c = tid - 64;
    float acc = b2f(bfc2[c]);
    for (int j = 0; j < NROI; ++j) acc += mid[j] * b2f(Wfc2[j * 2 + c]);
    out[b * 2 + c] = acc;
  }
  __syncthreads();
  if (tid < 6) {
    float acc = b2f(bd2[tid]);
#pragma unroll 8
    for (int k = 0; k < 64; ++k) acc += t[k] * b2f(Wd2[k * 6 + tid]);
    out[B * 2 + b * 6 + tid] = acc;
  }
}

// ---------------- launch ----------------

extern "C" void kernel_launch(void* const* d_in, const int* in_sizes, int n_in,
                              void* d_out, int out_size, void* d_ws, size_t ws_size,
                              hipStream_t stream) {
  const void* x  = d_in[0];
  const int*  ei = (const int*)d_in[1];
  const void* ea = d_in[2];
  float* out = (float*)d_out;

  int N = in_sizes[0] / NROI;   // 51200
  int E = in_sizes[2];          // 1638400
  int B = N / NROI;             // 256

  char* p = (char*)d_ws;
  auto carve = [&](size_t bytes) -> void* {
    void* r = (void*)p;
    p += (bytes + 255) & ~(size_t)255;
    return r;
  };
  int*   flags = (int*)carve(16);
  bf16*  cw    = (bf16*)carve(400000 * 2);
  float* dis   = (float*)carve((size_t)N * 4);
  int*   cnt   = (int*)carve((size_t)N * 4);
  int*   ptr   = (int*)carve(((size_t)N + 1) * 4);
  int*   pos   = (int*)carve((size_t)N * 4);
  int*   erow  = (int*)carve((size_t)E * 4);
  float* enorm = (float*)carve((size_t)E * 4);
  bf16*  h     = (bf16*)carve((size_t)N * 128 * 2);
  float* g     = (float*)carve((size_t)N * 128 * 4);
  float* out8  = (float*)carve((size_t)N * 8 * 4);
  float* z     = (float*)carve((size_t)B * NROI * 4);
  float* mu    = (float*)carve(NROI * 4);
  float* rv    = (float*)carve(NROI * 4);

  WArgs wa;
  int run = 0;
  int maxn = 0;
  for (int t = 0; t < 16; ++t) {
    wa.src[t] = d_in[3 + t];
    wa.n[t]   = in_sizes[3 + t];
    wa.off[t] = run;
    run += in_sizes[3 + t];
    if (in_sizes[3 + t] > maxn) maxn = in_sizes[3 + t];
  }
  const bf16* W1   = cw + wa.off[0];
  const bf16* b1   = cw + wa.off[1];
  const bf16* W2   = cw + wa.off[2];
  const bf16* b2   = cw + wa.off[3];
  const bf16* Wro  = cw + wa.off[4];
  const bf16* bro  = cw + wa.off[5];
  const bf16* Wfc1 = cw + wa.off[6];
  const bf16* bfc1 = cw + wa.off[7];
  const bf16* gam  = cw + wa.off[8];
  const bf16* bet  = cw + wa.off[9];
  const bf16* Wfc2 = cw + wa.off[10];
  const bf16* bfc2 = cw + wa.off[11];
  const bf16* Wd1  = cw + wa.off[12];
  const bf16* bd1  = cw + wa.off[13];
  const bf16* Wd2  = cw + wa.off[14];
  const bf16* bd2  = cw + wa.off[15];

  int nb = (N + 255) / 256;
  int eb = (E + 255) / 256;

  detect_kernel<<<1, 256, 0, stream>>>((const unsigned short*)x,
                                       (const unsigned*)ei, flags);
  dim3 wg((maxn + 255) / 256, 16);
  convert_weights<<<wg, 256, 0, stream>>>(wa, cw, flags);

  init_deg_cnt<<<nb, 256, 0, stream>>>(dis, cnt, N);
  edge_count<<<eb, 256, 0, stream>>>(ei, ea, flags, dis, cnt, E);
  make_dis<<<nb, 256, 0, stream>>>(dis, N);
  prefix_kernel<<<1, 1024, 0, stream>>>(cnt, ptr, pos, N);
  edge_scatter<<<eb, 256, 0, stream>>>(ei, ea, flags, dis, pos, erow, enorm, E);

  gemm_kernel<200, 128, 2><<<N / 64, 256, 0, stream>>>(x, W1, h, flags, 0);
  agg_mish<128><<<N / 2, 256, 0, stream>>>(h, dis, ptr, erow, enorm, b1, g, N);

  gemm_kernel<128, 64, 4><<<N / 64, 256, 0, stream>>>(g, W2, h, flags, 1);
  agg_mish<64><<<N / 4, 256, 0, stream>>>(h, dis, ptr, erow, enorm, b2, g, N);

  ro_kernel<<<(N * 8 + 255) / 256, 256, 0, stream>>>(g, Wro, bro, out8, N);
  fc1_kernel<<<B, 256, 0, stream>>>(out8, Wfc1, bfc1, z);
  bn_stats<<<NROI, 256, 0, stream>>>(z, mu, rv, B);
  head_kernel<<<B, 256, 0, stream>>>(z, mu, rv, gam, bet, Wfc2, bfc2,
                                     Wd1, bd1, Wd2, bd2, out, B);
}

// Round 4
// 738.447 us; speedup vs baseline: 1.5400x; 1.5400x over previous
//
#include <hip/hip_runtime.h>
#include <hip/hip_bf16.h>

typedef __hip_bfloat16 bf16;
typedef unsigned short ushort_t;

#define NROI 200

__device__ __forceinline__ float u2f(unsigned short u) {
  return __uint_as_float(((unsigned)u) << 16);
}
__device__ __forceinline__ float lo16(unsigned u) { return __uint_as_float(u << 16); }
__device__ __forceinline__ float hi16(unsigned u) { return __uint_as_float(u & 0xffff0000u); }
__device__ __forceinline__ float b2f(bf16 v) { return __bfloat162float(v); }
__device__ __forceinline__ unsigned short f2us(float f) {
  union { bf16 b; unsigned short u; } c;
  c.b = __float2bfloat16(f);
  return c.u;
}

__device__ __forceinline__ float mishf(float x) {
  float sp = (x > 20.0f) ? x : log1pf(expf(x));
  return x * tanhf(sp);
}

// ---------------- dtype detection ----------------
__global__ __launch_bounds__(256) void detect_kernel(const unsigned short* xu,
                                                     const unsigned* eiw,
                                                     int* flags) {
  int tid = threadIdx.x;
  int sane = 0, zodd = 0;
  for (int i = tid; i < 4096; i += 256) {
    unsigned short u = xu[2 * i];
    unsigned e = (u >> 7) & 0xFF;
    if (u == 0 || (e >= 100 && e <= 134)) sane++;
  }
  for (int i = tid; i < 4096; i += 256) {
    if (eiw[2 * i + 1] == 0) zodd++;
  }
  __shared__ int s1[256], s2[256];
  s1[tid] = sane; s2[tid] = zodd;
  __syncthreads();
  for (int off = 128; off > 0; off >>= 1) {
    if (tid < off) { s1[tid] += s1[tid + off]; s2[tid] += s2[tid + off]; }
    __syncthreads();
  }
  if (tid == 0) {
    flags[0] = (s1[0] < 2048) ? 1 : 0;
    flags[1] = (s2[0] > 2048) ? 1 : 0;
  }
}

// ---------------- weight canonicalization (-> bf16) ----------------
struct WArgs {
  const void* src[16];
  int n[16];
  int off[16];
};

__global__ __launch_bounds__(256) void convert_weights(WArgs a, bf16* base,
                                                       const int* flags) {
  int t = blockIdx.y;
  int i = blockIdx.x * 256 + threadIdx.x;
  if (i >= a.n[t]) return;
  bf16* dst = base + a.off[t];
  if (flags[0]) dst[i] = __float2bfloat16(((const float*)a.src[t])[i]);
  else ((unsigned short*)dst)[i] = ((const unsigned short*)a.src[t])[i];
}

// ---------------- graph preprocessing ----------------

__global__ void init_deg_cnt(float* deg, int* cnt, int N) {
  int i = blockIdx.x * blockDim.x + threadIdx.x;
  if (i < N) { deg[i] = 1.0f; cnt[i] = 0; }
}

__global__ void edge_count(const int* __restrict__ ei, const void* __restrict__ ea,
                           const int* __restrict__ flags,
                           float* deg, int* cnt, int E) {
  int e = blockIdx.x * blockDim.x + threadIdx.x;
  if (e >= E) return;
  int is64 = flags[1], isf32 = flags[0];
  int col = is64 ? ei[2 * (E + e)] : ei[E + e];
  float w = isf32 ? ((const float*)ea)[e] : u2f(((const unsigned short*)ea)[e]);
  atomicAdd(&deg[col], w);
  atomicAdd(&cnt[col], 1);
}

__global__ void make_dis(float* deg, int N) {
  int i = blockIdx.x * blockDim.x + threadIdx.x;
  if (i < N) deg[i] = rsqrtf(deg[i]);
}

__global__ __launch_bounds__(1024) void prefix_kernel(const int* __restrict__ cnt,
                                                      int* ptr, int* pos, int N) {
  __shared__ int pA[1024];
  __shared__ int pB[1024];
  int tid = threadIdx.x;
  int chunk = (N + 1023) / 1024;
  int start = tid * chunk;
  int end = start + chunk; if (end > N) end = N; if (start > N) start = N;
  int s = 0;
  for (int i = start; i < end; ++i) s += cnt[i];
  pA[tid] = s;
  __syncthreads();
  int* src = pA; int* dst = pB;
  for (int off = 1; off < 1024; off <<= 1) {
    int v = src[tid];
    if (tid >= off) v += src[tid - off];
    dst[tid] = v;
    __syncthreads();
    int* tmp = src; src = dst; dst = tmp;
  }
  int run = (tid == 0) ? 0 : src[tid - 1];
  for (int i = start; i < end; ++i) {
    ptr[i] = run; pos[i] = run; run += cnt[i];
  }
  if (tid == 1023) ptr[N] = run;
}

__global__ void edge_scatter(const int* __restrict__ ei, const void* __restrict__ ea,
                             const int* __restrict__ flags,
                             const float* __restrict__ dis, int* pos,
                             int* erow, float* enorm, int E) {
  int e = blockIdx.x * blockDim.x + threadIdx.x;
  if (e >= E) return;
  int is64 = flags[1], isf32 = flags[0];
  int r = is64 ? ei[2 * e] : ei[e];
  int c = is64 ? ei[2 * (E + e)] : ei[E + e];
  float w = isf32 ? ((const float*)ea)[e] : u2f(((const unsigned short*)ea)[e]);
  float nrm = dis[r] * w * dis[c];
  int idx = atomicAdd(&pos[c], 1);
  erow[idx] = r;
  enorm[idx] = nrm;
}

// ---------------- dense compute ----------------

// H[M,NC](bf16) = A[M,K] @ W[K,NC]; thread owns 2 rows x 4 cols.
template<int K, int NC>
__global__ __launch_bounds__(256) void gemm_kernel(const void* __restrict__ A,
                                                   const bf16* __restrict__ W,
                                                   bf16* __restrict__ H,
                                                   const int* __restrict__ flags,
                                                   int force_f32) {
  constexpr int G   = NC / 4;    // col groups
  constexpr int RG  = 256 / G;   // thread row-groups
  constexpr int RP  = RG * 2;    // rows per pass
  constexpr int RPB = 64;        // rows per block
  __shared__ unsigned short Ws[K * NC];
  __shared__ float As[RP * K];
  int tid = threadIdx.x;
  int isf32 = force_f32 ? 1 : flags[0];
  const unsigned short* Wu = (const unsigned short*)W;
  for (int i = tid; i < K * NC; i += 256) Ws[i] = Wu[i];
  const float* Af = (const float*)A;
  const unsigned short* Au = (const unsigned short*)A;
  int tx = tid % G, tyg = tid / G;
  size_t row0 = (size_t)blockIdx.x * RPB;
  unsigned short* Hu = (unsigned short*)H;
  for (int r = 0; r < RPB; r += RP) {
    __syncthreads();
    for (int i = tid; i < RP * K; i += 256) {
      int rr = i / K, kk = i - rr * K;
      size_t off = (row0 + r + rr) * K + kk;
      As[i] = isf32 ? Af[off] : u2f(Au[off]);
    }
    __syncthreads();
    float a00 = 0, a01 = 0, a02 = 0, a03 = 0;
    float a10 = 0, a11 = 0, a12 = 0, a13 = 0;
    const float* As0 = &As[(2 * tyg) * K];
    const float* As1 = &As[(2 * tyg + 1) * K];
#pragma unroll 4
    for (int k = 0; k < K; ++k) {
      float av0 = As0[k];
      float av1 = As1[k];
      ushort4 wv = *(const ushort4*)&Ws[k * NC + 4 * tx];
      float w0 = u2f(wv.x), w1 = u2f(wv.y), w2 = u2f(wv.z), w3 = u2f(wv.w);
      a00 += av0 * w0; a01 += av0 * w1; a02 += av0 * w2; a03 += av0 * w3;
      a10 += av1 * w0; a11 += av1 * w1; a12 += av1 * w2; a13 += av1 * w3;
    }
    size_t ro = row0 + r + 2 * tyg;
    ushort4 o0, o1;
    o0.x = f2us(a00); o0.y = f2us(a01); o0.z = f2us(a02); o0.w = f2us(a03);
    o1.x = f2us(a10); o1.y = f2us(a11); o1.z = f2us(a12); o1.w = f2us(a13);
    *(ushort4*)&Hu[ro * NC + 4 * tx] = o0;
    *(ushort4*)&Hu[(ro + 1) * NC + 4 * tx] = o1;
  }
}

// conv1 aggregation: one wave per node, lane owns 2 features (uint load), unroll 4.
__global__ __launch_bounds__(256) void agg_mish128(const unsigned* __restrict__ hu,
                                                   const float* __restrict__ dis,
                                                   const int* __restrict__ ptr,
                                                   const int* __restrict__ erow,
                                                   const float* __restrict__ enorm,
                                                   const bf16* __restrict__ bias,
                                                   float* __restrict__ g, int N) {
  int n = blockIdx.x * 4 + (threadIdx.x >> 6);
  int lane = threadIdx.x & 63;
  if (n >= N) return;
  float dn = dis[n];
  float self = dn * dn;
  unsigned u = hu[(size_t)n * 64 + lane];
  float acc0 = lo16(u) * self;
  float acc1 = hi16(u) * self;
  int e = ptr[n], e1 = ptr[n + 1];
  for (; e + 4 <= e1; e += 4) {
    int r0 = erow[e], r1 = erow[e + 1], r2 = erow[e + 2], r3 = erow[e + 3];
    unsigned u0 = hu[(size_t)r0 * 64 + lane];
    unsigned u1 = hu[(size_t)r1 * 64 + lane];
    unsigned u2 = hu[(size_t)r2 * 64 + lane];
    unsigned u3 = hu[(size_t)r3 * 64 + lane];
    float w0 = enorm[e], w1 = enorm[e + 1], w2 = enorm[e + 2], w3 = enorm[e + 3];
    acc0 += lo16(u0) * w0; acc1 += hi16(u0) * w0;
    acc0 += lo16(u1) * w1; acc1 += hi16(u1) * w1;
    acc0 += lo16(u2) * w2; acc1 += hi16(u2) * w2;
    acc0 += lo16(u3) * w3; acc1 += hi16(u3) * w3;
  }
  for (; e < e1; ++e) {
    int r = erow[e];
    unsigned uu = hu[(size_t)r * 64 + lane];
    float w = enorm[e];
    acc0 += lo16(uu) * w; acc1 += hi16(uu) * w;
  }
  unsigned bb = ((const unsigned*)bias)[lane];
  float2 o;
  o.x = mishf(acc0 + lo16(bb));
  o.y = mishf(acc1 + hi16(bb));
  *(float2*)&g[(size_t)n * 128 + 2 * lane] = o;
}

// conv2 aggregation fused with readout: half-wave per node (lane owns 2 of 64 feats),
// then out8[n,c] = mish-row @ Wro[:,c] via butterfly reduce.
__global__ __launch_bounds__(256) void agg_mish64_ro(const unsigned* __restrict__ hu,
                                                     const float* __restrict__ dis,
                                                     const int* __restrict__ ptr,
                                                     const int* __restrict__ erow,
                                                     const float* __restrict__ enorm,
                                                     const bf16* __restrict__ bias,
                                                     const bf16* __restrict__ Wro,
                                                     const bf16* __restrict__ bro,
                                                     float* __restrict__ out8, int N) {
  int w = threadIdx.x >> 6;
  int lane = threadIdx.x & 63;
  int half = lane >> 5, l5 = lane & 31;
  int n = blockIdx.x * 8 + w * 2 + half;
  if (n >= N) return;
  float dn = dis[n];
  float self = dn * dn;
  unsigned u = hu[(size_t)n * 32 + l5];
  float acc0 = lo16(u) * self;
  float acc1 = hi16(u) * self;
  int e = ptr[n], e1 = ptr[n + 1];
  for (; e + 4 <= e1; e += 4) {
    int r0 = erow[e], r1 = erow[e + 1], r2 = erow[e + 2], r3 = erow[e + 3];
    unsigned u0 = hu[(size_t)r0 * 32 + l5];
    unsigned u1 = hu[(size_t)r1 * 32 + l5];
    unsigned u2 = hu[(size_t)r2 * 32 + l5];
    unsigned u3 = hu[(size_t)r3 * 32 + l5];
    float w0 = enorm[e], w1 = enorm[e + 1], w2 = enorm[e + 2], w3 = enorm[e + 3];
    acc0 += lo16(u0) * w0; acc1 += hi16(u0) * w0;
    acc0 += lo16(u1) * w1; acc1 += hi16(u1) * w1;
    acc0 += lo16(u2) * w2; acc1 += hi16(u2) * w2;
    acc0 += lo16(u3) * w3; acc1 += hi16(u3) * w3;
  }
  for (; e < e1; ++e) {
    int r = erow[e];
    unsigned uu = hu[(size_t)r * 32 + l5];
    float wv = enorm[e];
    acc0 += lo16(uu) * wv; acc1 += hi16(uu) * wv;
  }
  unsigned bb = ((const unsigned*)bias)[l5];
  float m0 = mishf(acc0 + lo16(bb));
  float m1 = mishf(acc1 + hi16(bb));
  // readout partials: rows 2*l5, 2*l5+1 of Wro[64][8]
  uint4 r0 = ((const uint4*)Wro)[2 * l5];
  uint4 r1 = ((const uint4*)Wro)[2 * l5 + 1];
  float p0 = m0 * lo16(r0.x) + m1 * lo16(r1.x);
  float p1 = m0 * hi16(r0.x) + m1 * hi16(r1.x);
  float p2 = m0 * lo16(r0.y) + m1 * lo16(r1.y);
  float p3 = m0 * hi16(r0.y) + m1 * hi16(r1.y);
  float p4 = m0 * lo16(r0.z) + m1 * lo16(r1.z);
  float p5 = m0 * hi16(r0.z) + m1 * hi16(r1.z);
  float p6 = m0 * lo16(r0.w) + m1 * lo16(r1.w);
  float p7 = m0 * hi16(r0.w) + m1 * hi16(r1.w);
#pragma unroll
  for (int off = 16; off >= 1; off >>= 1) {
    p0 += __shfl_xor(p0, off);
    p1 += __shfl_xor(p1, off);
    p2 += __shfl_xor(p2, off);
    p3 += __shfl_xor(p3, off);
    p4 += __shfl_xor(p4, off);
    p5 += __shfl_xor(p5, off);
    p6 += __shfl_xor(p6, off);
    p7 += __shfl_xor(p7, off);
  }
  if (l5 == 0) {
    float4 q0, q1;
    q0.x = mishf(p0 + b2f(bro[0])); q0.y = mishf(p1 + b2f(bro[1]));
    q0.z = mishf(p2 + b2f(bro[2])); q0.w = mishf(p3 + b2f(bro[3]));
    q1.x = mishf(p4 + b2f(bro[4])); q1.y = mishf(p5 + b2f(bro[5]));
    q1.z = mishf(p6 + b2f(bro[6])); q1.w = mishf(p7 + b2f(bro[7]));
    *(float4*)&out8[(size_t)n * 8] = q0;
    *(float4*)&out8[(size_t)n * 8 + 4] = q1;
  }
}

// z[b,j] = feat[b,:1600] @ Wfc1[:,j] + bfc1[j]
__global__ __launch_bounds__(256) void fc1_kernel(const float* __restrict__ feat,
                                                  const bf16* __restrict__ W,
                                                  const bf16* __restrict__ bias,
                                                  float* __restrict__ z) {
  __shared__ float fr[1600];
  int b = blockIdx.x, tid = threadIdx.x;
  for (int i = tid; i < 1600; i += 256) fr[i] = feat[(size_t)b * 1600 + i];
  __syncthreads();
  if (tid < NROI) {
    float acc = b2f(bias[tid]);
#pragma unroll 8
    for (int k = 0; k < 1600; ++k) acc += fr[k] * b2f(W[k * NROI + tid]);
    z[b * NROI + tid] = acc;
  }
}

__global__ __launch_bounds__(256) void bn_stats(const float* __restrict__ z,
                                                float* mu, float* rvar, int B) {
  int j = blockIdx.x;
  int tid = threadIdx.x;
  float v = z[tid * NROI + j];
  float s = v, q = v * v;
  for (int off = 32; off > 0; off >>= 1) {
    s += __shfl_down(s, off);
    q += __shfl_down(q, off);
  }
  __shared__ float ss[4], qq[4];
  int w = tid >> 6, lane = tid & 63;
  if (lane == 0) { ss[w] = s; qq[w] = q; }
  __syncthreads();
  if (tid == 0) {
    float S = ss[0] + ss[1] + ss[2] + ss[3];
    float Q = qq[0] + qq[1] + qq[2] + qq[3];
    float m = S / (float)B;
    float var = Q / (float)B - m * m;
    mu[j] = m;
    rvar[j] = rsqrtf(var + 1e-5f);
  }
}

__global__ __launch_bounds__(256) void head_kernel(const float* __restrict__ z,
                                                   const float* __restrict__ mu,
                                                   const float* __restrict__ rvar,
                                                   const bf16* __restrict__ gamma,
                                                   const bf16* __restrict__ beta,
                                                   const bf16* __restrict__ Wfc2,
                                                   const bf16* __restrict__ bfc2,
                                                   const bf16* __restrict__ Wd1,
                                                   const bf16* __restrict__ bd1,
                                                   const bf16* __restrict__ Wd2,
                                                   const bf16* __restrict__ bd2,
                                                   float* __restrict__ out, int B) {
  __shared__ float mid[NROI];
  __shared__ float t[64];
  int b = blockIdx.x, tid = threadIdx.x;
  if (tid < NROI) {
    float v = (z[b * NROI + tid] - mu[tid]) * rvar[tid] * b2f(gamma[tid]) + b2f(beta[tid]);
    mid[tid] = mishf(v);
  }
  __syncthreads();
  if (tid < 64) {
    float acc = b2f(bd1[tid]);
#pragma unroll 8
    for (int j = 0; j < NROI; ++j) acc += mid[j] * b2f(Wd1[j * 64 + tid]);
    t[tid] = fmaxf(acc, 0.0f);
  }
  if (tid >= 64 && tid < 66) {
    int c = tid - 64;
    float acc = b2f(bfc2[c]);
    for (int j = 0; j < NROI; ++j) acc += mid[j] * b2f(Wfc2[j * 2 + c]);
    out[b * 2 + c] = acc;
  }
  __syncthreads();
  if (tid < 6) {
    float acc = b2f(bd2[tid]);
#pragma unroll 8
    for (int k = 0; k < 64; ++k) acc += t[k] * b2f(Wd2[k * 6 + tid]);
    out[B * 2 + b * 6 + tid] = acc;
  }
}

// ---------------- launch ----------------

extern "C" void kernel_launch(void* const* d_in, const int* in_sizes, int n_in,
                              void* d_out, int out_size, void* d_ws, size_t ws_size,
                              hipStream_t stream) {
  const void* x  = d_in[0];
  const int*  ei = (const int*)d_in[1];
  const void* ea = d_in[2];
  float* out = (float*)d_out;

  int N = in_sizes[0] / NROI;   // 51200
  int E = in_sizes[2];          // 1638400
  int B = N / NROI;             // 256

  char* p = (char*)d_ws;
  auto carve = [&](size_t bytes) -> void* {
    void* r = (void*)p;
    p += (bytes + 255) & ~(size_t)255;
    return r;
  };
  int*   flags = (int*)carve(16);
  bf16*  cw    = (bf16*)carve(400000 * 2);
  float* dis   = (float*)carve((size_t)N * 4);
  int*   cnt   = (int*)carve((size_t)N * 4);
  int*   ptr   = (int*)carve(((size_t)N + 1) * 4);
  int*   pos   = (int*)carve((size_t)N * 4);
  int*   erow  = (int*)carve((size_t)E * 4);
  float* enorm = (float*)carve((size_t)E * 4);
  bf16*  h     = (bf16*)carve((size_t)N * 128 * 2);
  float* g     = (float*)carve((size_t)N * 128 * 4);
  float* out8  = (float*)carve((size_t)N * 8 * 4);
  float* z     = (float*)carve((size_t)B * NROI * 4);
  float* mu    = (float*)carve(NROI * 4);
  float* rv    = (float*)carve(NROI * 4);

  WArgs wa;
  int run = 0;
  int maxn = 0;
  for (int t = 0; t < 16; ++t) {
    wa.src[t] = d_in[3 + t];
    wa.n[t]   = in_sizes[3 + t];
    wa.off[t] = run;
    run += in_sizes[3 + t];
    if (in_sizes[3 + t] > maxn) maxn = in_sizes[3 + t];
  }
  const bf16* W1   = cw + wa.off[0];
  const bf16* b1   = cw + wa.off[1];
  const bf16* W2   = cw + wa.off[2];
  const bf16* b2   = cw + wa.off[3];
  const bf16* Wro  = cw + wa.off[4];
  const bf16* bro  = cw + wa.off[5];
  const bf16* Wfc1 = cw + wa.off[6];
  const bf16* bfc1 = cw + wa.off[7];
  const bf16* gam  = cw + wa.off[8];
  const bf16* bet  = cw + wa.off[9];
  const bf16* Wfc2 = cw + wa.off[10];
  const bf16* bfc2 = cw + wa.off[11];
  const bf16* Wd1  = cw + wa.off[12];
  const bf16* bd1  = cw + wa.off[13];
  const bf16* Wd2  = cw + wa.off[14];
  const bf16* bd2  = cw + wa.off[15];

  int nb = (N + 255) / 256;
  int eb = (E + 255) / 256;

  detect_kernel<<<1, 256, 0, stream>>>((const unsigned short*)x,
                                       (const unsigned*)ei, flags);
  dim3 wg((maxn + 255) / 256, 16);
  convert_weights<<<wg, 256, 0, stream>>>(wa, cw, flags);

  init_deg_cnt<<<nb, 256, 0, stream>>>(dis, cnt, N);
  edge_count<<<eb, 256, 0, stream>>>(ei, ea, flags, dis, cnt, E);
  make_dis<<<nb, 256, 0, stream>>>(dis, N);
  prefix_kernel<<<1, 1024, 0, stream>>>(cnt, ptr, pos, N);
  edge_scatter<<<eb, 256, 0, stream>>>(ei, ea, flags, dis, pos, erow, enorm, E);

  gemm_kernel<200, 128><<<N / 64, 256, 0, stream>>>(x, W1, h, flags, 0);
  agg_mish128<<<N / 4, 256, 0, stream>>>((const unsigned*)h, dis, ptr, erow,
                                         enorm, b1, g, N);

  gemm_kernel<128, 64><<<N / 64, 256, 0, stream>>>(g, W2, h, flags, 1);
  agg_mish64_ro<<<N / 8, 256, 0, stream>>>((const unsigned*)h, dis, ptr, erow,
                                           enorm, b2, Wro, bro, out8, N);

  fc1_kernel<<<B, 256, 0, stream>>>(out8, Wfc1, bfc1, z);
  bn_stats<<<NROI, 256, 0, stream>>>(z, mu, rv, B);
  head_kernel<<<B, 256, 0, stream>>>(z, mu, rv, gam, bet, Wfc2, bfc2,
                                     Wd1, bd1, Wd2, bd2, out, B);
}

// Round 5
// 575.723 us; speedup vs baseline: 1.9753x; 1.2826x over previous
//
#include <hip/hip_runtime.h>
#include <hip/hip_bf16.h>

typedef __hip_bfloat16 bf16;
typedef __attribute__((ext_vector_type(8))) short short8;
typedef __attribute__((ext_vector_type(4))) float f32x4;

#define NROI 200

__device__ __forceinline__ float u2f(unsigned short u) {
  return __uint_as_float(((unsigned)u) << 16);
}
__device__ __forceinline__ float lo16(unsigned u) { return __uint_as_float(u << 16); }
__device__ __forceinline__ float hi16(unsigned u) { return __uint_as_float(u & 0xffff0000u); }
__device__ __forceinline__ float b2f(bf16 v) { return __bfloat162float(v); }
__device__ __forceinline__ unsigned short f2us(float f) {
  union { bf16 b; unsigned short u; } c;
  c.b = __float2bfloat16(f);
  return c.u;
}

__device__ __forceinline__ float mishf(float x) {
  float sp = (x > 20.0f) ? x : log1pf(expf(x));
  return x * tanhf(sp);
}

// ---------------- dtype detection ----------------
__global__ __launch_bounds__(256) void detect_kernel(const unsigned short* xu,
                                                     const unsigned* eiw,
                                                     int* flags) {
  int tid = threadIdx.x;
  int sane = 0, zodd = 0;
  for (int i = tid; i < 4096; i += 256) {
    unsigned short u = xu[2 * i];
    unsigned e = (u >> 7) & 0xFF;
    if (u == 0 || (e >= 100 && e <= 134)) sane++;
  }
  for (int i = tid; i < 4096; i += 256) {
    if (eiw[2 * i + 1] == 0) zodd++;
  }
  __shared__ int s1[256], s2[256];
  s1[tid] = sane; s2[tid] = zodd;
  __syncthreads();
  for (int off = 128; off > 0; off >>= 1) {
    if (tid < off) { s1[tid] += s1[tid + off]; s2[tid] += s2[tid + off]; }
    __syncthreads();
  }
  if (tid == 0) {
    flags[0] = (s1[0] < 2048) ? 1 : 0;
    flags[1] = (s2[0] > 2048) ? 1 : 0;
  }
}

// ---------------- weight canonicalization (-> bf16) ----------------
struct WArgs {
  const void* src[16];
  int n[16];
  int off[16];
};

__global__ __launch_bounds__(256) void convert_weights(WArgs a, bf16* base,
                                                       const int* flags) {
  int t = blockIdx.y;
  int i = blockIdx.x * 256 + threadIdx.x;
  if (i >= a.n[t]) return;
  bf16* dst = base + a.off[t];
  if (flags[0]) dst[i] = __float2bfloat16(((const float*)a.src[t])[i]);
  else ((unsigned short*)dst)[i] = ((const unsigned short*)a.src[t])[i];
}

// W[K][NC] bf16 -> dst[kc][nt][lane][8] B-fragment order (zero-pad k>=K)
__global__ __launch_bounds__(256) void swizzleW(const unsigned short* __restrict__ src,
                                                unsigned short* __restrict__ dst,
                                                int K, int KC, int NT) {
  int idx = blockIdx.x * 256 + threadIdx.x;
  int total = KC * NT * 512;
  if (idx >= total) return;
  int e = idx & 7;
  int l = (idx >> 3) & 63;
  int t = (idx >> 9) % NT;
  int kc = idx / (NT * 512);
  int k = kc * 32 + (l >> 4) * 8 + e;
  int c = t * 16 + (l & 15);
  dst[idx] = (k < K) ? src[k * (NT * 16) + c] : 0;
}

// x[N][200] (f32 or bf16) -> xb[N][224] bf16, zero-padded
__global__ __launch_bounds__(256) void xbf_convert(const void* __restrict__ x,
                                                   unsigned short* __restrict__ xb,
                                                   const int* __restrict__ flags,
                                                   int N) {
  long long idx = (long long)blockIdx.x * 256 + threadIdx.x;
  long long total = (long long)N * 224;
  if (idx >= total) return;
  int c = (int)(idx % 224);
  long long n = idx / 224;
  unsigned short v = 0;
  if (c < 200) {
    if (flags[0]) v = f2us(((const float*)x)[n * 200 + c]);
    else v = ((const unsigned short*)x)[n * 200 + c];
  }
  xb[idx] = v;
}

// ---------------- graph preprocessing ----------------

__global__ void init_dc(unsigned long long* dc, int N) {
  int i = blockIdx.x * blockDim.x + threadIdx.x;
  if (i < N) dc[i] = 0ull;
}

// one packed 64-bit atomic per edge: cnt in bits>=40, weight 40-bit fixed point (2^-32)
__global__ void edge_count(const int* __restrict__ ei, const void* __restrict__ ea,
                           const int* __restrict__ flags,
                           unsigned long long* dc, int E) {
  int e = blockIdx.x * blockDim.x + threadIdx.x;
  if (e >= E) return;
  int is64 = flags[1], isf32 = flags[0];
  int col = is64 ? ei[2 * (E + e)] : ei[E + e];
  float w = isf32 ? ((const float*)ea)[e] : u2f(((const unsigned short*)ea)[e]);
  unsigned long long p = (1ull << 40) | (unsigned long long)(w * 4294967296.0f);
  atomicAdd(&dc[col], p);
}

__global__ void make_dis(const unsigned long long* __restrict__ dc, float* dis, int N) {
  int i = blockIdx.x * blockDim.x + threadIdx.x;
  if (i < N) {
    float wsum = (float)(dc[i] & 0xFFFFFFFFFFull) * 2.3283064365386963e-10f;
    dis[i] = rsqrtf(1.0f + wsum);
  }
}

__global__ __launch_bounds__(1024) void prefix_kernel(const unsigned long long* __restrict__ dc,
                                                      int* ptr, int* pos, int N) {
  __shared__ int pA[1024];
  __shared__ int pB[1024];
  int tid = threadIdx.x;
  int chunk = (N + 1023) / 1024;
  int start = tid * chunk;
  int end = start + chunk; if (end > N) end = N; if (start > N) start = N;
  int s = 0;
  for (int i = start; i < end; ++i) s += (int)(dc[i] >> 40);
  pA[tid] = s;
  __syncthreads();
  int* src = pA; int* dst = pB;
  for (int off = 1; off < 1024; off <<= 1) {
    int v = src[tid];
    if (tid >= off) v += src[tid - off];
    dst[tid] = v;
    __syncthreads();
    int* tmp = src; src = dst; dst = tmp;
  }
  int run = (tid == 0) ? 0 : src[tid - 1];
  for (int i = start; i < end; ++i) {
    ptr[i] = run; pos[i] = run; run += (int)(dc[i] >> 40);
  }
  if (tid == 1023) ptr[N] = run;
}

__global__ void edge_scatter(const int* __restrict__ ei, const void* __restrict__ ea,
                             const int* __restrict__ flags,
                             const float* __restrict__ dis, int* pos,
                             int2* __restrict__ epair, int E) {
  int e = blockIdx.x * blockDim.x + threadIdx.x;
  if (e >= E) return;
  int is64 = flags[1], isf32 = flags[0];
  int r = is64 ? ei[2 * e] : ei[e];
  int c = is64 ? ei[2 * (E + e)] : ei[E + e];
  float w = isf32 ? ((const float*)ea)[e] : u2f(((const unsigned short*)ea)[e]);
  float nrm = dis[r] * w * dis[c];
  int idx = atomicAdd(&pos[c], 1);
  int2 pr; pr.x = r; pr.y = __float_as_int(nrm);
  epair[idx] = pr;
}

// ---------------- MFMA GEMM ----------------
// H[M][NT*16](bf16) = A[M][KC*32](bf16) @ Wswz; block = 4 waves x 16 rows.
template<int KC, int NT>
__global__ __launch_bounds__(256) void gemm_mfma(const unsigned short* __restrict__ Abf,
                                                 const unsigned short* __restrict__ Wswz,
                                                 unsigned short* __restrict__ H,
                                                 int M) {
  int wid = threadIdx.x >> 6, lane = threadIdx.x & 63;
  int row0 = (blockIdx.x * 4 + wid) * 16;
  if (row0 >= M) return;
  constexpr int K = KC * 32;
  constexpr int NC = NT * 16;
  f32x4 acc[NT];
#pragma unroll
  for (int t = 0; t < NT; ++t) acc[t] = {0.f, 0.f, 0.f, 0.f};
  size_t arow = (size_t)(row0 + (lane & 15)) * K + (lane >> 4) * 8;
#pragma unroll
  for (int kc = 0; kc < KC; ++kc) {
    short8 a = *(const short8*)&Abf[arow + kc * 32];
#pragma unroll
    for (int t = 0; t < NT; ++t) {
      short8 b = *(const short8*)&Wswz[((kc * NT + t) * 64 + lane) * 8];
      acc[t] = __builtin_amdgcn_mfma_f32_16x16x32_bf16(a, b, acc[t], 0, 0, 0);
    }
  }
  int orow = row0 + (lane >> 4) * 4;
  int ocol = lane & 15;
#pragma unroll
  for (int t = 0; t < NT; ++t)
#pragma unroll
    for (int r = 0; r < 4; ++r)
      H[(size_t)(orow + r) * NC + t * 16 + ocol] = f2us(acc[t][r]);
}

// ---------------- aggregations ----------------

// conv1: one wave per node, lane owns 2 of 128 feats; unroll 8; writes g bf16-packed.
__global__ __launch_bounds__(256) void agg_mish128(const unsigned* __restrict__ hu,
                                                   const float* __restrict__ dis,
                                                   const int* __restrict__ ptr,
                                                   const int2* __restrict__ ep,
                                                   const bf16* __restrict__ bias,
                                                   unsigned* __restrict__ g, int N) {
  int n = blockIdx.x * 4 + (threadIdx.x >> 6);
  int lane = threadIdx.x & 63;
  float dn = dis[n];
  float self = dn * dn;
  unsigned u = hu[(size_t)n * 64 + lane];
  float acc0 = lo16(u) * self;
  float acc1 = hi16(u) * self;
  int e = ptr[n], e1 = ptr[n + 1];
  for (; e + 8 <= e1; e += 8) {
    int2 p[8]; unsigned uu[8];
#pragma unroll
    for (int j = 0; j < 8; ++j) p[j] = ep[e + j];
#pragma unroll
    for (int j = 0; j < 8; ++j) uu[j] = hu[(size_t)p[j].x * 64 + lane];
#pragma unroll
    for (int j = 0; j < 8; ++j) {
      float w = __int_as_float(p[j].y);
      acc0 += lo16(uu[j]) * w;
      acc1 += hi16(uu[j]) * w;
    }
  }
  for (; e < e1; ++e) {
    int2 pp = ep[e];
    unsigned uu = hu[(size_t)pp.x * 64 + lane];
    float w = __int_as_float(pp.y);
    acc0 += lo16(uu) * w;
    acc1 += hi16(uu) * w;
  }
  unsigned bb = ((const unsigned*)bias)[lane];
  float m0 = mishf(acc0 + lo16(bb));
  float m1 = mishf(acc1 + hi16(bb));
  g[(size_t)n * 64 + lane] = ((unsigned)f2us(m1) << 16) | f2us(m0);
}

// conv2 + readout fused: half-wave per node (lane owns 2 of 64 feats); butterfly reduce.
__global__ __launch_bounds__(256) void agg_mish64_ro(const unsigned* __restrict__ hu,
                                                     const float* __restrict__ dis,
                                                     const int* __restrict__ ptr,
                                                     const int2* __restrict__ ep,
                                                     const bf16* __restrict__ bias,
                                                     const bf16* __restrict__ Wro,
                                                     const bf16* __restrict__ bro,
                                                     float* __restrict__ out8, int N) {
  int w = threadIdx.x >> 6;
  int lane = threadIdx.x & 63;
  int half = lane >> 5, l5 = lane & 31;
  int n = blockIdx.x * 8 + w * 2 + half;
  float dn = dis[n];
  float self = dn * dn;
  unsigned u = hu[(size_t)n * 32 + l5];
  float acc0 = lo16(u) * self;
  float acc1 = hi16(u) * self;
  int e = ptr[n], e1 = ptr[n + 1];
  for (; e + 8 <= e1; e += 8) {
    int2 p[8]; unsigned uu[8];
#pragma unroll
    for (int j = 0; j < 8; ++j) p[j] = ep[e + j];
#pragma unroll
    for (int j = 0; j < 8; ++j) uu[j] = hu[(size_t)p[j].x * 32 + l5];
#pragma unroll
    for (int j = 0; j < 8; ++j) {
      float wv = __int_as_float(p[j].y);
      acc0 += lo16(uu[j]) * wv;
      acc1 += hi16(uu[j]) * wv;
    }
  }
  for (; e < e1; ++e) {
    int2 pp = ep[e];
    unsigned uu = hu[(size_t)pp.x * 32 + l5];
    float wv = __int_as_float(pp.y);
    acc0 += lo16(uu) * wv;
    acc1 += hi16(uu) * wv;
  }
  unsigned bb = ((const unsigned*)bias)[l5];
  float m0 = mishf(acc0 + lo16(bb));
  float m1 = mishf(acc1 + hi16(bb));
  uint4 r0 = ((const uint4*)Wro)[2 * l5];
  uint4 r1 = ((const uint4*)Wro)[2 * l5 + 1];
  float p0 = m0 * lo16(r0.x) + m1 * lo16(r1.x);
  float p1 = m0 * hi16(r0.x) + m1 * hi16(r1.x);
  float p2 = m0 * lo16(r0.y) + m1 * lo16(r1.y);
  float p3 = m0 * hi16(r0.y) + m1 * hi16(r1.y);
  float p4 = m0 * lo16(r0.z) + m1 * lo16(r1.z);
  float p5 = m0 * hi16(r0.z) + m1 * hi16(r1.z);
  float p6 = m0 * lo16(r0.w) + m1 * lo16(r1.w);
  float p7 = m0 * hi16(r0.w) + m1 * hi16(r1.w);
#pragma unroll
  for (int off = 16; off >= 1; off >>= 1) {
    p0 += __shfl_xor(p0, off);
    p1 += __shfl_xor(p1, off);
    p2 += __shfl_xor(p2, off);
    p3 += __shfl_xor(p3, off);
    p4 += __shfl_xor(p4, off);
    p5 += __shfl_xor(p5, off);
    p6 += __shfl_xor(p6, off);
    p7 += __shfl_xor(p7, off);
  }
  if (l5 == 0) {
    float4 q0, q1;
    q0.x = mishf(p0 + b2f(bro[0])); q0.y = mishf(p1 + b2f(bro[1]));
    q0.z = mishf(p2 + b2f(bro[2])); q0.w = mishf(p3 + b2f(bro[3]));
    q1.x = mishf(p4 + b2f(bro[4])); q1.y = mishf(p5 + b2f(bro[5]));
    q1.z = mishf(p6 + b2f(bro[6])); q1.w = mishf(p7 + b2f(bro[7]));
    *(float4*)&out8[(size_t)n * 8] = q0;
    *(float4*)&out8[(size_t)n * 8 + 4] = q1;
  }
}

// ---------------- dense tail ----------------

__global__ __launch_bounds__(256) void fc1_kernel(const float* __restrict__ feat,
                                                  const bf16* __restrict__ W,
                                                  const bf16* __restrict__ bias,
                                                  float* __restrict__ z) {
  __shared__ float fr[1600];
  int b = blockIdx.x, tid = threadIdx.x;
  for (int i = tid; i < 1600; i += 256) fr[i] = feat[(size_t)b * 1600 + i];
  __syncthreads();
  if (tid < NROI) {
    float acc = b2f(bias[tid]);
#pragma unroll 8
    for (int k = 0; k < 1600; ++k) acc += fr[k] * b2f(W[k * NROI + tid]);
    z[b * NROI + tid] = acc;
  }
}

__global__ __launch_bounds__(256) void bn_stats(const float* __restrict__ z,
                                                float* mu, float* rvar, int B) {
  int j = blockIdx.x;
  int tid = threadIdx.x;
  float v = z[tid * NROI + j];
  float s = v, q = v * v;
  for (int off = 32; off > 0; off >>= 1) {
    s += __shfl_down(s, off);
    q += __shfl_down(q, off);
  }
  __shared__ float ss[4], qq[4];
  int w = tid >> 6, lane = tid & 63;
  if (lane == 0) { ss[w] = s; qq[w] = q; }
  __syncthreads();
  if (tid == 0) {
    float S = ss[0] + ss[1] + ss[2] + ss[3];
    float Q = qq[0] + qq[1] + qq[2] + qq[3];
    float m = S / (float)B;
    float var = Q / (float)B - m * m;
    mu[j] = m;
    rvar[j] = rsqrtf(var + 1e-5f);
  }
}

__global__ __launch_bounds__(256) void head_kernel(const float* __restrict__ z,
                                                   const float* __restrict__ mu,
                                                   const float* __restrict__ rvar,
                                                   const bf16* __restrict__ gamma,
                                                   const bf16* __restrict__ beta,
                                                   const bf16* __restrict__ Wfc2,
                                                   const bf16* __restrict__ bfc2,
                                                   const bf16* __restrict__ Wd1,
                                                   const bf16* __restrict__ bd1,
                                                   const bf16* __restrict__ Wd2,
                                                   const bf16* __restrict__ bd2,
                                                   float* __restrict__ out, int B) {
  __shared__ float mid[NROI];
  __shared__ float t[64];
  int b = blockIdx.x, tid = threadIdx.x;
  if (tid < NROI) {
    float v = (z[b * NROI + tid] - mu[tid]) * rvar[tid] * b2f(gamma[tid]) + b2f(beta[tid]);
    mid[tid] = mishf(v);
  }
  __syncthreads();
  if (tid < 64) {
    float acc = b2f(bd1[tid]);
#pragma unroll 8
    for (int j = 0; j < NROI; ++j) acc += mid[j] * b2f(Wd1[j * 64 + tid]);
    t[tid] = fmaxf(acc, 0.0f);
  }
  if (tid >= 64 && tid < 66) {
    int c = tid - 64;
    float acc = b2f(bfc2[c]);
    for (int j = 0; j < NROI; ++j) acc += mid[j] * b2f(Wfc2[j * 2 + c]);
    out[b * 2 + c] = acc;
  }
  __syncthreads();
  if (tid < 6) {
    float acc = b2f(bd2[tid]);
#pragma unroll 8
    for (int k = 0; k < 64; ++k) acc += t[k] * b2f(Wd2[k * 6 + tid]);
    out[B * 2 + b * 6 + tid] = acc;
  }
}

// ---------------- launch ----------------

extern "C" void kernel_launch(void* const* d_in, const int* in_sizes, int n_in,
                              void* d_out, int out_size, void* d_ws, size_t ws_size,
                              hipStream_t stream) {
  const void* x  = d_in[0];
  const int*  ei = (const int*)d_in[1];
  const void* ea = d_in[2];
  float* out = (float*)d_out;

  int N = in_sizes[0] / NROI;   // 51200
  int E = in_sizes[2];          // 1638400
  int B = N / NROI;             // 256

  char* p = (char*)d_ws;
  auto carve = [&](size_t bytes) -> void* {
    void* r = (void*)p;
    p += (bytes + 255) & ~(size_t)255;
    return r;
  };
  int*   flags = (int*)carve(16);
  bf16*  cw    = (bf16*)carve(400000 * 2);
  float* dis   = (float*)carve((size_t)N * 4);
  unsigned long long* dc = (unsigned long long*)carve((size_t)N * 8);
  int*   ptr   = (int*)carve(((size_t)N + 1) * 4);
  int*   pos   = (int*)carve((size_t)N * 4);
  int2*  epair = (int2*)carve((size_t)E * 8);
  unsigned short* h = (unsigned short*)carve((size_t)N * 128 * 2);
  // union: xbf [N][224] bf16 (dead after gemm1) overlaps g [N][128] bf16
  char* xg = (char*)carve((size_t)N * 224 * 2);
  unsigned short* xbf = (unsigned short*)xg;
  unsigned* g = (unsigned*)xg;
  unsigned short* w1swz = (unsigned short*)carve(7 * 8 * 512 * 2);
  unsigned short* w2swz = (unsigned short*)carve(4 * 4 * 512 * 2);
  float* out8  = (float*)carve((size_t)N * 8 * 4);
  float* z     = (float*)carve((size_t)B * NROI * 4);
  float* mu    = (float*)carve(NROI * 4);
  float* rv    = (float*)carve(NROI * 4);

  WArgs wa;
  int run = 0;
  int maxn = 0;
  for (int t = 0; t < 16; ++t) {
    wa.src[t] = d_in[3 + t];
    wa.n[t]   = in_sizes[3 + t];
    wa.off[t] = run;
    run += in_sizes[3 + t];
    if (in_sizes[3 + t] > maxn) maxn = in_sizes[3 + t];
  }
  const bf16* W1   = cw + wa.off[0];
  const bf16* b1   = cw + wa.off[1];
  const bf16* W2   = cw + wa.off[2];
  const bf16* b2   = cw + wa.off[3];
  const bf16* Wro  = cw + wa.off[4];
  const bf16* bro  = cw + wa.off[5];
  const bf16* Wfc1 = cw + wa.off[6];
  const bf16* bfc1 = cw + wa.off[7];
  const bf16* gam  = cw + wa.off[8];
  const bf16* bet  = cw + wa.off[9];
  const bf16* Wfc2 = cw + wa.off[10];
  const bf16* bfc2 = cw + wa.off[11];
  const bf16* Wd1  = cw + wa.off[12];
  const bf16* bd1  = cw + wa.off[13];
  const bf16* Wd2  = cw + wa.off[14];
  const bf16* bd2  = cw + wa.off[15];

  int nb = (N + 255) / 256;
  int eb = (E + 255) / 256;

  detect_kernel<<<1, 256, 0, stream>>>((const unsigned short*)x,
                                       (const unsigned*)ei, flags);
  dim3 wg((maxn + 255) / 256, 16);
  convert_weights<<<wg, 256, 0, stream>>>(wa, cw, flags);
  swizzleW<<<(7 * 8 * 512 + 255) / 256, 256, 0, stream>>>(
      (const unsigned short*)W1, w1swz, 200, 7, 8);
  swizzleW<<<(4 * 4 * 512 + 255) / 256, 256, 0, stream>>>(
      (const unsigned short*)W2, w2swz, 128, 4, 4);

  init_dc<<<nb, 256, 0, stream>>>(dc, N);
  edge_count<<<eb, 256, 0, stream>>>(ei, ea, flags, dc, E);
  make_dis<<<nb, 256, 0, stream>>>(dc, dis, N);
  prefix_kernel<<<1, 1024, 0, stream>>>(dc, ptr, pos, N);
  edge_scatter<<<eb, 256, 0, stream>>>(ei, ea, flags, dis, pos, epair, E);

  long long xtot = (long long)N * 224;
  xbf_convert<<<(int)((xtot + 255) / 256), 256, 0, stream>>>(x, xbf, flags, N);
  gemm_mfma<7, 8><<<N / 64, 256, 0, stream>>>(xbf, w1swz, h, N);
  agg_mish128<<<N / 4, 256, 0, stream>>>((const unsigned*)h, dis, ptr, epair,
                                         b1, g, N);
  gemm_mfma<4, 4><<<N / 64, 256, 0, stream>>>((const unsigned short*)g, w2swz, h, N);
  agg_mish64_ro<<<N / 8, 256, 0, stream>>>((const unsigned*)h, dis, ptr, epair,
                                           b2, Wro, bro, out8, N);

  fc1_kernel<<<B, 256, 0, stream>>>(out8, Wfc1, bfc1, z);
  bn_stats<<<NROI, 256, 0, stream>>>(z, mu, rv, B);
  head_kernel<<<B, 256, 0, stream>>>(z, mu, rv, gam, bet, Wfc2, bfc2,
                                     Wd1, bd1, Wd2, bd2, out, B);
}

// Round 6
// 410.475 us; speedup vs baseline: 2.7705x; 1.4026x over previous
//
#include <hip/hip_runtime.h>
#include <hip/hip_bf16.h>

typedef __hip_bfloat16 bf16;
typedef __attribute__((ext_vector_type(8))) short short8;
typedef __attribute__((ext_vector_type(4))) float f32x4;

#define NROI 200

__device__ __forceinline__ float u2f(unsigned short u) {
  return __uint_as_float(((unsigned)u) << 16);
}
__device__ __forceinline__ float lo16(unsigned u) { return __uint_as_float(u << 16); }
__device__ __forceinline__ float hi16(unsigned u) { return __uint_as_float(u & 0xffff0000u); }
__device__ __forceinline__ float b2f(bf16 v) { return __bfloat162float(v); }
__device__ __forceinline__ unsigned short f2us(float f) {
  union { bf16 b; unsigned short u; } c;
  c.b = __float2bfloat16(f);
  return c.u;
}

__device__ __forceinline__ float mishf(float x) {
  float sp = (x > 20.0f) ? x : log1pf(expf(x));
  return x * tanhf(sp);
}

// ---------------- dtype detection ----------------
__global__ __launch_bounds__(256) void detect_kernel(const unsigned short* xu,
                                                     const unsigned* eiw,
                                                     int* flags) {
  int tid = threadIdx.x;
  int sane = 0, zodd = 0;
  for (int i = tid; i < 4096; i += 256) {
    unsigned short u = xu[2 * i];
    unsigned e = (u >> 7) & 0xFF;
    if (u == 0 || (e >= 100 && e <= 134)) sane++;
  }
  for (int i = tid; i < 4096; i += 256) {
    if (eiw[2 * i + 1] == 0) zodd++;
  }
  __shared__ int s1[256], s2[256];
  s1[tid] = sane; s2[tid] = zodd;
  __syncthreads();
  for (int off = 128; off > 0; off >>= 1) {
    if (tid < off) { s1[tid] += s1[tid + off]; s2[tid] += s2[tid + off]; }
    __syncthreads();
  }
  if (tid == 0) {
    flags[0] = (s1[0] < 2048) ? 1 : 0;
    flags[1] = (s2[0] > 2048) ? 1 : 0;
  }
}

// ---------------- weight canonicalization (-> bf16) ----------------
struct WArgs {
  const void* src[16];
  int n[16];
  int off[16];
};

__global__ __launch_bounds__(256) void convert_weights(WArgs a, bf16* base,
                                                       const int* flags) {
  int t = blockIdx.y;
  int i = blockIdx.x * 256 + threadIdx.x;
  if (i >= a.n[t]) return;
  bf16* dst = base + a.off[t];
  if (flags[0]) dst[i] = __float2bfloat16(((const float*)a.src[t])[i]);
  else ((unsigned short*)dst)[i] = ((const unsigned short*)a.src[t])[i];
}

// W[K][NC] bf16 -> dst[kc][nt][lane][8] B-fragment order (zero-pad k>=K)
__global__ __launch_bounds__(256) void swizzleW(const unsigned short* __restrict__ src,
                                                unsigned short* __restrict__ dst,
                                                int K, int KC, int NT) {
  int idx = blockIdx.x * 256 + threadIdx.x;
  int total = KC * NT * 512;
  if (idx >= total) return;
  int e = idx & 7;
  int l = (idx >> 3) & 63;
  int t = (idx >> 9) % NT;
  int kc = idx / (NT * 512);
  int k = kc * 32 + (l >> 4) * 8 + e;
  int c = t * 16 + (l & 15);
  dst[idx] = (k < K) ? src[k * (NT * 16) + c] : 0;
}

// x[N][200] (f32 or bf16) -> xb[N][224] bf16, zero-padded
__global__ __launch_bounds__(256) void xbf_convert(const void* __restrict__ x,
                                                   unsigned short* __restrict__ xb,
                                                   const int* __restrict__ flags,
                                                   int N) {
  long long idx = (long long)blockIdx.x * 256 + threadIdx.x;
  long long total = (long long)N * 224;
  if (idx >= total) return;
  int c = (int)(idx % 224);
  long long n = idx / 224;
  unsigned short v = 0;
  if (c < 200) {
    if (flags[0]) v = f2us(((const float*)x)[n * 200 + c]);
    else v = ((const unsigned short*)x)[n * 200 + c];
  }
  xb[idx] = v;
}

// ---------------- graph preprocessing ----------------

__global__ void init_dc(unsigned long long* dc, int N) {
  int i = blockIdx.x * blockDim.x + threadIdx.x;
  if (i < N) dc[i] = 0ull;
}

// one packed 64-bit atomic per edge: cnt in bits>=40, weight 40-bit fixed point (2^-32).
// The returned old value's count field is this edge's rank within its dest node.
__global__ void edge_count(const int* __restrict__ ei, const void* __restrict__ ea,
                           const int* __restrict__ flags,
                           unsigned long long* dc, int* __restrict__ rank, int E) {
  int e = blockIdx.x * blockDim.x + threadIdx.x;
  if (e >= E) return;
  int is64 = flags[1], isf32 = flags[0];
  int col = is64 ? ei[2 * (E + e)] : ei[E + e];
  float w = isf32 ? ((const float*)ea)[e] : u2f(((const unsigned short*)ea)[e]);
  unsigned long long p = (1ull << 40) | (unsigned long long)(w * 4294967296.0f);
  unsigned long long old = atomicAdd(&dc[col], p);
  rank[e] = (int)(old >> 40);
}

__global__ void make_dis(const unsigned long long* __restrict__ dc, float* dis, int N) {
  int i = blockIdx.x * blockDim.x + threadIdx.x;
  if (i < N) {
    float wsum = (float)(dc[i] & 0xFFFFFFFFFFull) * 2.3283064365386963e-10f;
    dis[i] = rsqrtf(1.0f + wsum);
  }
}

// ------- 3-phase multi-block exclusive scan of degree counts -> ptr -------
__global__ __launch_bounds__(256) void scan_phase1(const unsigned long long* __restrict__ dc,
                                                   int* __restrict__ bsum, int N) {
  __shared__ int ts[256];
  int tid = threadIdx.x;
  int base = blockIdx.x * 1024 + tid * 4;
  int s = 0;
#pragma unroll
  for (int j = 0; j < 4; ++j)
    if (base + j < N) s += (int)(dc[base + j] >> 40);
  ts[tid] = s;
  __syncthreads();
  for (int off = 128; off > 0; off >>= 1) {
    if (tid < off) ts[tid] += ts[tid + off];
    __syncthreads();
  }
  if (tid == 0) bsum[blockIdx.x] = ts[0];
}

__global__ __launch_bounds__(64) void scan_phase2(const int* __restrict__ bsum,
                                                  int* __restrict__ bpre,
                                                  int* __restrict__ ptr, int nb, int N) {
  if (threadIdx.x == 0) {
    int run = 0;
    for (int i = 0; i < nb; ++i) { bpre[i] = run; run += bsum[i]; }
    ptr[N] = run;
  }
}

__global__ __launch_bounds__(256) void scan_phase3(const unsigned long long* __restrict__ dc,
                                                   const int* __restrict__ bpre,
                                                   int* __restrict__ ptr, int N) {
  __shared__ int ts[256];
  int tid = threadIdx.x;
  int base = blockIdx.x * 1024 + tid * 4;
  int c0 = 0, c1 = 0, c2 = 0, c3 = 0;
  if (base + 0 < N) c0 = (int)(dc[base + 0] >> 40);
  if (base + 1 < N) c1 = (int)(dc[base + 1] >> 40);
  if (base + 2 < N) c2 = (int)(dc[base + 2] >> 40);
  if (base + 3 < N) c3 = (int)(dc[base + 3] >> 40);
  ts[tid] = c0 + c1 + c2 + c3;
  __syncthreads();
  for (int off = 1; off < 256; off <<= 1) {
    int v = ts[tid];
    if (tid >= off) v += ts[tid - off];
    __syncthreads();
    ts[tid] = v;
    __syncthreads();
  }
  int run = bpre[blockIdx.x] + (tid ? ts[tid - 1] : 0);
  if (base + 0 < N) { ptr[base + 0] = run; run += c0; }
  if (base + 1 < N) { ptr[base + 1] = run; run += c1; }
  if (base + 2 < N) { ptr[base + 2] = run; run += c2; }
  if (base + 3 < N) { ptr[base + 3] = run; run += c3; }
}

// atomic-free scatter: slot = ptr[col] + rank[e]
__global__ void edge_scatter(const int* __restrict__ ei, const void* __restrict__ ea,
                             const int* __restrict__ flags,
                             const float* __restrict__ dis,
                             const int* __restrict__ ptr,
                             const int* __restrict__ rank,
                             int2* __restrict__ epair, int E) {
  int e = blockIdx.x * blockDim.x + threadIdx.x;
  if (e >= E) return;
  int is64 = flags[1], isf32 = flags[0];
  int r = is64 ? ei[2 * e] : ei[e];
  int c = is64 ? ei[2 * (E + e)] : ei[E + e];
  float w = isf32 ? ((const float*)ea)[e] : u2f(((const unsigned short*)ea)[e]);
  float nrm = dis[r] * w * dis[c];
  int idx = ptr[c] + rank[e];
  int2 pr; pr.x = r; pr.y = __float_as_int(nrm);
  epair[idx] = pr;
}

// ---------------- MFMA GEMM ----------------
// H[M][NT*16](bf16) = A[M][KC*32](bf16) @ Wswz; block = 4 waves x 16 rows.
template<int KC, int NT>
__global__ __launch_bounds__(256) void gemm_mfma(const unsigned short* __restrict__ Abf,
                                                 const unsigned short* __restrict__ Wswz,
                                                 unsigned short* __restrict__ H,
                                                 int M) {
  int wid = threadIdx.x >> 6, lane = threadIdx.x & 63;
  int row0 = (blockIdx.x * 4 + wid) * 16;
  if (row0 >= M) return;
  constexpr int K = KC * 32;
  constexpr int NC = NT * 16;
  f32x4 acc[NT];
#pragma unroll
  for (int t = 0; t < NT; ++t) acc[t] = {0.f, 0.f, 0.f, 0.f};
  size_t arow = (size_t)(row0 + (lane & 15)) * K + (lane >> 4) * 8;
#pragma unroll
  for (int kc = 0; kc < KC; ++kc) {
    short8 a = *(const short8*)&Abf[arow + kc * 32];
#pragma unroll
    for (int t = 0; t < NT; ++t) {
      short8 b = *(const short8*)&Wswz[((kc * NT + t) * 64 + lane) * 8];
      acc[t] = __builtin_amdgcn_mfma_f32_16x16x32_bf16(a, b, acc[t], 0, 0, 0);
    }
  }
  int orow = row0 + (lane >> 4) * 4;
  int ocol = lane & 15;
#pragma unroll
  for (int t = 0; t < NT; ++t)
#pragma unroll
    for (int r = 0; r < 4; ++r)
      H[(size_t)(orow + r) * NC + t * 16 + ocol] = f2us(acc[t][r]);
}

// ---------------- aggregations ----------------

// conv1: one wave per node, lane owns 2 of 128 feats; unroll 8; writes g bf16-packed.
__global__ __launch_bounds__(256) void agg_mish128(const unsigned* __restrict__ hu,
                                                   const float* __restrict__ dis,
                                                   const int* __restrict__ ptr,
                                                   const int2* __restrict__ ep,
                                                   const bf16* __restrict__ bias,
                                                   unsigned* __restrict__ g, int N) {
  int n = blockIdx.x * 4 + (threadIdx.x >> 6);
  int lane = threadIdx.x & 63;
  float dn = dis[n];
  float self = dn * dn;
  unsigned u = hu[(size_t)n * 64 + lane];
  float acc0 = lo16(u) * self;
  float acc1 = hi16(u) * self;
  int e = ptr[n], e1 = ptr[n + 1];
  for (; e + 8 <= e1; e += 8) {
    int2 p[8]; unsigned uu[8];
#pragma unroll
    for (int j = 0; j < 8; ++j) p[j] = ep[e + j];
#pragma unroll
    for (int j = 0; j < 8; ++j) uu[j] = hu[(size_t)p[j].x * 64 + lane];
#pragma unroll
    for (int j = 0; j < 8; ++j) {
      float w = __int_as_float(p[j].y);
      acc0 += lo16(uu[j]) * w;
      acc1 += hi16(uu[j]) * w;
    }
  }
  for (; e < e1; ++e) {
    int2 pp = ep[e];
    unsigned uu = hu[(size_t)pp.x * 64 + lane];
    float w = __int_as_float(pp.y);
    acc0 += lo16(uu) * w;
    acc1 += hi16(uu) * w;
  }
  unsigned bb = ((const unsigned*)bias)[lane];
  float m0 = mishf(acc0 + lo16(bb));
  float m1 = mishf(acc1 + hi16(bb));
  g[(size_t)n * 64 + lane] = ((unsigned)f2us(m1) << 16) | f2us(m0);
}

// conv2 + readout fused: half-wave per node (lane owns 2 of 64 feats); butterfly reduce.
__global__ __launch_bounds__(256) void agg_mish64_ro(const unsigned* __restrict__ hu,
                                                     const float* __restrict__ dis,
                                                     const int* __restrict__ ptr,
                                                     const int2* __restrict__ ep,
                                                     const bf16* __restrict__ bias,
                                                     const bf16* __restrict__ Wro,
                                                     const bf16* __restrict__ bro,
                                                     float* __restrict__ out8, int N) {
  int w = threadIdx.x >> 6;
  int lane = threadIdx.x & 63;
  int half = lane >> 5, l5 = lane & 31;
  int n = blockIdx.x * 8 + w * 2 + half;
  float dn = dis[n];
  float self = dn * dn;
  unsigned u = hu[(size_t)n * 32 + l5];
  float acc0 = lo16(u) * self;
  float acc1 = hi16(u) * self;
  int e = ptr[n], e1 = ptr[n + 1];
  for (; e + 8 <= e1; e += 8) {
    int2 p[8]; unsigned uu[8];
#pragma unroll
    for (int j = 0; j < 8; ++j) p[j] = ep[e + j];
#pragma unroll
    for (int j = 0; j < 8; ++j) uu[j] = hu[(size_t)p[j].x * 32 + l5];
#pragma unroll
    for (int j = 0; j < 8; ++j) {
      float wv = __int_as_float(p[j].y);
      acc0 += lo16(uu[j]) * wv;
      acc1 += hi16(uu[j]) * wv;
    }
  }
  for (; e < e1; ++e) {
    int2 pp = ep[e];
    unsigned uu = hu[(size_t)pp.x * 32 + l5];
    float wv = __int_as_float(pp.y);
    acc0 += lo16(uu) * wv;
    acc1 += hi16(uu) * wv;
  }
  unsigned bb = ((const unsigned*)bias)[l5];
  float m0 = mishf(acc0 + lo16(bb));
  float m1 = mishf(acc1 + hi16(bb));
  uint4 r0 = ((const uint4*)Wro)[2 * l5];
  uint4 r1 = ((const uint4*)Wro)[2 * l5 + 1];
  float p0 = m0 * lo16(r0.x) + m1 * lo16(r1.x);
  float p1 = m0 * hi16(r0.x) + m1 * hi16(r1.x);
  float p2 = m0 * lo16(r0.y) + m1 * lo16(r1.y);
  float p3 = m0 * hi16(r0.y) + m1 * hi16(r1.y);
  float p4 = m0 * lo16(r0.z) + m1 * lo16(r1.z);
  float p5 = m0 * hi16(r0.z) + m1 * hi16(r1.z);
  float p6 = m0 * lo16(r0.w) + m1 * lo16(r1.w);
  float p7 = m0 * hi16(r0.w) + m1 * hi16(r1.w);
#pragma unroll
  for (int off = 16; off >= 1; off >>= 1) {
    p0 += __shfl_xor(p0, off);
    p1 += __shfl_xor(p1, off);
    p2 += __shfl_xor(p2, off);
    p3 += __shfl_xor(p3, off);
    p4 += __shfl_xor(p4, off);
    p5 += __shfl_xor(p5, off);
    p6 += __shfl_xor(p6, off);
    p7 += __shfl_xor(p7, off);
  }
  if (l5 == 0) {
    float4 q0, q1;
    q0.x = mishf(p0 + b2f(bro[0])); q0.y = mishf(p1 + b2f(bro[1]));
    q0.z = mishf(p2 + b2f(bro[2])); q0.w = mishf(p3 + b2f(bro[3]));
    q1.x = mishf(p4 + b2f(bro[4])); q1.y = mishf(p5 + b2f(bro[5]));
    q1.z = mishf(p6 + b2f(bro[6])); q1.w = mishf(p7 + b2f(bro[7]));
    *(float4*)&out8[(size_t)n * 8] = q0;
    *(float4*)&out8[(size_t)n * 8 + 4] = q1;
  }
}

// ---------------- dense tail ----------------

__global__ __launch_bounds__(256) void fc1_kernel(const float* __restrict__ feat,
                                                  const bf16* __restrict__ W,
                                                  const bf16* __restrict__ bias,
                                                  float* __restrict__ z) {
  __shared__ float fr[1600];
  int b = blockIdx.x, tid = threadIdx.x;
  for (int i = tid; i < 1600; i += 256) fr[i] = feat[(size_t)b * 1600 + i];
  __syncthreads();
  if (tid < NROI) {
    float acc = b2f(bias[tid]);
#pragma unroll 8
    for (int k = 0; k < 1600; ++k) acc += fr[k] * b2f(W[k * NROI + tid]);
    z[b * NROI + tid] = acc;
  }
}

__global__ __launch_bounds__(256) void bn_stats(const float* __restrict__ z,
                                                float* mu, float* rvar, int B) {
  int j = blockIdx.x;
  int tid = threadIdx.x;
  float v = z[tid * NROI + j];
  float s = v, q = v * v;
  for (int off = 32; off > 0; off >>= 1) {
    s += __shfl_down(s, off);
    q += __shfl_down(q, off);
  }
  __shared__ float ss[4], qq[4];
  int w = tid >> 6, lane = tid & 63;
  if (lane == 0) { ss[w] = s; qq[w] = q; }
  __syncthreads();
  if (tid == 0) {
    float S = ss[0] + ss[1] + ss[2] + ss[3];
    float Q = qq[0] + qq[1] + qq[2] + qq[3];
    float m = S / (float)B;
    float var = Q / (float)B - m * m;
    mu[j] = m;
    rvar[j] = rsqrtf(var + 1e-5f);
  }
}

__global__ __launch_bounds__(256) void head_kernel(const float* __restrict__ z,
                                                   const float* __restrict__ mu,
                                                   const float* __restrict__ rvar,
                                                   const bf16* __restrict__ gamma,
                                                   const bf16* __restrict__ beta,
                                                   const bf16* __restrict__ Wfc2,
                                                   const bf16* __restrict__ bfc2,
                                                   const bf16* __restrict__ Wd1,
                                                   const bf16* __restrict__ bd1,
                                                   const bf16* __restrict__ Wd2,
                                                   const bf16* __restrict__ bd2,
                                                   float* __restrict__ out, int B) {
  __shared__ float mid[NROI];
  __shared__ float t[64];
  int b = blockIdx.x, tid = threadIdx.x;
  if (tid < NROI) {
    float v = (z[b * NROI + tid] - mu[tid]) * rvar[tid] * b2f(gamma[tid]) + b2f(beta[tid]);
    mid[tid] = mishf(v);
  }
  __syncthreads();
  if (tid < 64) {
    float acc = b2f(bd1[tid]);
#pragma unroll 8
    for (int j = 0; j < NROI; ++j) acc += mid[j] * b2f(Wd1[j * 64 + tid]);
    t[tid] = fmaxf(acc, 0.0f);
  }
  if (tid >= 64 && tid < 66) {
    int c = tid - 64;
    float acc = b2f(bfc2[c]);
    for (int j = 0; j < NROI; ++j) acc += mid[j] * b2f(Wfc2[j * 2 + c]);
    out[b * 2 + c] = acc;
  }
  __syncthreads();
  if (tid < 6) {
    float acc = b2f(bd2[tid]);
#pragma unroll 8
    for (int k = 0; k < 64; ++k) acc += t[k] * b2f(Wd2[k * 6 + tid]);
    out[B * 2 + b * 6 + tid] = acc;
  }
}

// ---------------- launch ----------------

extern "C" void kernel_launch(void* const* d_in, const int* in_sizes, int n_in,
                              void* d_out, int out_size, void* d_ws, size_t ws_size,
                              hipStream_t stream) {
  const void* x  = d_in[0];
  const int*  ei = (const int*)d_in[1];
  const void* ea = d_in[2];
  float* out = (float*)d_out;

  int N = in_sizes[0] / NROI;   // 51200
  int E = in_sizes[2];          // 1638400
  int B = N / NROI;             // 256

  char* p = (char*)d_ws;
  auto carve = [&](size_t bytes) -> void* {
    void* r = (void*)p;
    p += (bytes + 255) & ~(size_t)255;
    return r;
  };
  int*   flags = (int*)carve(16);
  bf16*  cw    = (bf16*)carve(400000 * 2);
  float* dis   = (float*)carve((size_t)N * 4);
  unsigned long long* dc = (unsigned long long*)carve((size_t)N * 8);
  int*   ptr   = (int*)carve(((size_t)N + 1) * 4);
  int*   bsum  = (int*)carve(1024);
  int*   bpre  = (int*)carve(1024);
  int2*  epair = (int2*)carve((size_t)E * 8);
  unsigned short* h = (unsigned short*)carve((size_t)N * 128 * 2);
  // union region: rank[E] (dead after edge_scatter) / xbf[N][224] bf16 (dead after
  // gemm1) / g[N][128] bf16 — all used in disjoint stream-ordered phases.
  size_t xg_bytes = (size_t)N * 224 * 2;
  size_t rk_bytes = (size_t)E * 4;
  char* xg = (char*)carve(xg_bytes > rk_bytes ? xg_bytes : rk_bytes);
  int* rank = (int*)xg;
  unsigned short* xbf = (unsigned short*)xg;
  unsigned* g = (unsigned*)xg;
  unsigned short* w1swz = (unsigned short*)carve(7 * 8 * 512 * 2);
  unsigned short* w2swz = (unsigned short*)carve(4 * 4 * 512 * 2);
  float* out8  = (float*)carve((size_t)N * 8 * 4);
  float* z     = (float*)carve((size_t)B * NROI * 4);
  float* mu    = (float*)carve(NROI * 4);
  float* rv    = (float*)carve(NROI * 4);

  WArgs wa;
  int run = 0;
  int maxn = 0;
  for (int t = 0; t < 16; ++t) {
    wa.src[t] = d_in[3 + t];
    wa.n[t]   = in_sizes[3 + t];
    wa.off[t] = run;
    run += in_sizes[3 + t];
    if (in_sizes[3 + t] > maxn) maxn = in_sizes[3 + t];
  }
  const bf16* W1   = cw + wa.off[0];
  const bf16* b1   = cw + wa.off[1];
  const bf16* W2   = cw + wa.off[2];
  const bf16* b2   = cw + wa.off[3];
  const bf16* Wro  = cw + wa.off[4];
  const bf16* bro  = cw + wa.off[5];
  const bf16* Wfc1 = cw + wa.off[6];
  const bf16* bfc1 = cw + wa.off[7];
  const bf16* gam  = cw + wa.off[8];
  const bf16* bet  = cw + wa.off[9];
  const bf16* Wfc2 = cw + wa.off[10];
  const bf16* bfc2 = cw + wa.off[11];
  const bf16* Wd1  = cw + wa.off[12];
  const bf16* bd1  = cw + wa.off[13];
  const bf16* Wd2  = cw + wa.off[14];
  const bf16* bd2  = cw + wa.off[15];

  int nb = (N + 255) / 256;
  int eb = (E + 255) / 256;
  int nscan = (N + 1023) / 1024;   // 50

  detect_kernel<<<1, 256, 0, stream>>>((const unsigned short*)x,
                                       (const unsigned*)ei, flags);
  dim3 wg((maxn + 255) / 256, 16);
  convert_weights<<<wg, 256, 0, stream>>>(wa, cw, flags);
  swizzleW<<<(7 * 8 * 512 + 255) / 256, 256, 0, stream>>>(
      (const unsigned short*)W1, w1swz, 200, 7, 8);
  swizzleW<<<(4 * 4 * 512 + 255) / 256, 256, 0, stream>>>(
      (const unsigned short*)W2, w2swz, 128, 4, 4);

  init_dc<<<nb, 256, 0, stream>>>(dc, N);
  edge_count<<<eb, 256, 0, stream>>>(ei, ea, flags, dc, rank, E);
  make_dis<<<nb, 256, 0, stream>>>(dc, dis, N);
  scan_phase1<<<nscan, 256, 0, stream>>>(dc, bsum, N);
  scan_phase2<<<1, 64, 0, stream>>>(bsum, bpre, ptr, nscan, N);
  scan_phase3<<<nscan, 256, 0, stream>>>(dc, bpre, ptr, N);
  edge_scatter<<<eb, 256, 0, stream>>>(ei, ea, flags, dis, ptr, rank, epair, E);

  long long xtot = (long long)N * 224;
  xbf_convert<<<(int)((xtot + 255) / 256), 256, 0, stream>>>(x, xbf, flags, N);
  gemm_mfma<7, 8><<<N / 64, 256, 0, stream>>>(xbf, w1swz, h, N);
  agg_mish128<<<N / 4, 256, 0, stream>>>((const unsigned*)h, dis, ptr, epair,
                                         b1, g, N);
  gemm_mfma<4, 4><<<N / 64, 256, 0, stream>>>((const unsigned short*)g, w2swz, h, N);
  agg_mish64_ro<<<N / 8, 256, 0, stream>>>((const unsigned*)h, dis, ptr, epair,
                                           b2, Wro, bro, out8, N);

  fc1_kernel<<<B, 256, 0, stream>>>(out8, Wfc1, bfc1, z);
  bn_stats<<<NROI, 256, 0, stream>>>(z, mu, rv, B);
  head_kernel<<<B, 256, 0, stream>>>(z, mu, rv, gam, bet, Wfc2, bfc2,
                                     Wd1, bd1, Wd2, bd2, out, B);
}

// Round 7
// 385.796 us; speedup vs baseline: 2.9477x; 1.0640x over previous
//
#include <hip/hip_runtime.h>
#include <hip/hip_bf16.h>

typedef __hip_bfloat16 bf16;
typedef __attribute__((ext_vector_type(8))) short short8;
typedef __attribute__((ext_vector_type(4))) float f32x4;

#define NROI 200

__device__ __forceinline__ float u2f(unsigned short u) {
  return __uint_as_float(((unsigned)u) << 16);
}
__device__ __forceinline__ float lo16(unsigned u) { return __uint_as_float(u << 16); }
__device__ __forceinline__ float hi16(unsigned u) { return __uint_as_float(u & 0xffff0000u); }
__device__ __forceinline__ float b2f(bf16 v) { return __bfloat162float(v); }
__device__ __forceinline__ unsigned short f2us(float f) {
  union { bf16 b; unsigned short u; } c;
  c.b = __float2bfloat16(f);
  return c.u;
}

__device__ __forceinline__ float mishf(float x) {
  float sp = (x > 20.0f) ? x : log1pf(expf(x));
  return x * tanhf(sp);
}

// ---------------- dtype detection ----------------
__global__ __launch_bounds__(256) void detect_kernel(const unsigned short* xu,
                                                     const unsigned* eiw,
                                                     int* flags) {
  int tid = threadIdx.x;
  int sane = 0, zodd = 0;
  for (int i = tid; i < 4096; i += 256) {
    unsigned short u = xu[2 * i];
    unsigned e = (u >> 7) & 0xFF;
    if (u == 0 || (e >= 100 && e <= 134)) sane++;
  }
  for (int i = tid; i < 4096; i += 256) {
    if (eiw[2 * i + 1] == 0) zodd++;
  }
  __shared__ int s1[256], s2[256];
  s1[tid] = sane; s2[tid] = zodd;
  __syncthreads();
  for (int off = 128; off > 0; off >>= 1) {
    if (tid < off) { s1[tid] += s1[tid + off]; s2[tid] += s2[tid + off]; }
    __syncthreads();
  }
  if (tid == 0) {
    flags[0] = (s1[0] < 2048) ? 1 : 0;
    flags[1] = (s2[0] > 2048) ? 1 : 0;
  }
}

// ---------------- weight canonicalization (-> bf16) ----------------
struct WArgs {
  const void* src[16];
  int n[16];
  int off[16];
};

__global__ __launch_bounds__(256) void convert_weights(WArgs a, bf16* base,
                                                       const int* flags) {
  int t = blockIdx.y;
  int i = blockIdx.x * 256 + threadIdx.x;
  if (i >= a.n[t]) return;
  bf16* dst = base + a.off[t];
  if (flags[0]) dst[i] = __float2bfloat16(((const float*)a.src[t])[i]);
  else ((unsigned short*)dst)[i] = ((const unsigned short*)a.src[t])[i];
}

// W[K][NC] bf16 -> dst[kc][nt][lane][8] B-fragment order (zero-pad k>=K)
__global__ __launch_bounds__(256) void swizzleW(const unsigned short* __restrict__ src,
                                                unsigned short* __restrict__ dst,
                                                int K, int KC, int NT) {
  int idx = blockIdx.x * 256 + threadIdx.x;
  int total = KC * NT * 512;
  if (idx >= total) return;
  int e = idx & 7;
  int l = (idx >> 3) & 63;
  int t = (idx >> 9) % NT;
  int kc = idx / (NT * 512);
  int k = kc * 32 + (l >> 4) * 8 + e;
  int c = t * 16 + (l & 15);
  dst[idx] = (k < K) ? src[k * (NT * 16) + c] : 0;
}

// x[N][200] (f32 or bf16) -> xb[N][224] bf16, zero-padded
__global__ __launch_bounds__(256) void xbf_convert(const void* __restrict__ x,
                                                   unsigned short* __restrict__ xb,
                                                   const int* __restrict__ flags,
                                                   int N) {
  long long idx = (long long)blockIdx.x * 256 + threadIdx.x;
  long long total = (long long)N * 224;
  if (idx >= total) return;
  int c = (int)(idx % 224);
  long long n = idx / 224;
  unsigned short v = 0;
  if (c < 200) {
    if (flags[0]) v = f2us(((const float*)x)[n * 200 + c]);
    else v = ((const unsigned short*)x)[n * 200 + c];
  }
  xb[idx] = v;
}

// ---------------- graph preprocessing ----------------

__global__ void init_dc8(unsigned long long* dc8, long long M) {
  long long i = (long long)blockIdx.x * blockDim.x + threadIdx.x;
  if (i < M) dc8[i] = 0ull;
}

// XCD-local packed atomic per edge: replica chosen by physical XCC_ID; the
// WORKGROUP-scope RMW executes in the issuing XCD's own L2 (no sc1). No two
// XCDs touch the same replica, so no cross-L2 coherence is needed during the
// kernel; end-of-kernel release publishes the replicas to later kernels.
// cnt in bits>=40, weight 40-bit fixed point (2^-32). rank = (xcd<<20)|local.
__global__ void edge_count(const int* __restrict__ ei, const void* __restrict__ ea,
                           const int* __restrict__ flags,
                           unsigned long long* dc8, int* __restrict__ rank,
                           int N, int E) {
  int e = blockIdx.x * blockDim.x + threadIdx.x;
  if (e >= E) return;
  unsigned xcd;
  asm("s_getreg_b32 %0, hwreg(HW_REG_XCC_ID)" : "=s"(xcd));
  xcd &= 7;
  int is64 = flags[1], isf32 = flags[0];
  int col = is64 ? ei[2 * (E + e)] : ei[E + e];
  float w = isf32 ? ((const float*)ea)[e] : u2f(((const unsigned short*)ea)[e]);
  unsigned long long p = (1ull << 40) | (unsigned long long)(w * 4294967296.0f);
  unsigned long long old = __hip_atomic_fetch_add(&dc8[(size_t)xcd * N + col], p,
                                                  __ATOMIC_RELAXED,
                                                  __HIP_MEMORY_SCOPE_WORKGROUP);
  rank[e] = ((int)xcd << 20) | (int)(old >> 40);
}

// per-node: total count -> cnt, dis = rsqrt(1+wsum), per-XCD exclusive bases -> xb
__global__ __launch_bounds__(256) void xcd_base(const unsigned long long* __restrict__ dc8,
                                                float* __restrict__ dis,
                                                int* __restrict__ cnt,
                                                unsigned short* __restrict__ xb, int N) {
  int n = blockIdx.x * 256 + threadIdx.x;
  if (n >= N) return;
  int run = 0;
  unsigned long long ws = 0;
  unsigned short loc[8];
#pragma unroll
  for (int x = 0; x < 8; ++x) {
    unsigned long long v = dc8[(size_t)x * N + n];
    loc[x] = (unsigned short)run;
    run += (int)(v >> 40);
    ws += v & 0xFFFFFFFFFFull;
  }
  cnt[n] = run;
  dis[n] = rsqrtf(1.0f + (float)ws * 2.3283064365386963e-10f);
  uint4 o;
  o.x = (unsigned)loc[0] | ((unsigned)loc[1] << 16);
  o.y = (unsigned)loc[2] | ((unsigned)loc[3] << 16);
  o.z = (unsigned)loc[4] | ((unsigned)loc[5] << 16);
  o.w = (unsigned)loc[6] | ((unsigned)loc[7] << 16);
  ((uint4*)xb)[n] = o;
}

// ------- 3-phase multi-block exclusive scan of cnt -> ptr -------
__global__ __launch_bounds__(256) void scan_phase1(const int* __restrict__ cnt,
                                                   int* __restrict__ bsum, int N) {
  __shared__ int ts[256];
  int tid = threadIdx.x;
  int base = blockIdx.x * 1024 + tid * 4;
  int s = 0;
#pragma unroll
  for (int j = 0; j < 4; ++j)
    if (base + j < N) s += cnt[base + j];
  ts[tid] = s;
  __syncthreads();
  for (int off = 128; off > 0; off >>= 1) {
    if (tid < off) ts[tid] += ts[tid + off];
    __syncthreads();
  }
  if (tid == 0) bsum[blockIdx.x] = ts[0];
}

__global__ __launch_bounds__(64) void scan_phase2(const int* __restrict__ bsum,
                                                  int* __restrict__ bpre,
                                                  int* __restrict__ ptr, int nb, int N) {
  if (threadIdx.x == 0) {
    int run = 0;
    for (int i = 0; i < nb; ++i) { bpre[i] = run; run += bsum[i]; }
    ptr[N] = run;
  }
}

__global__ __launch_bounds__(256) void scan_phase3(const int* __restrict__ cnt,
                                                   const int* __restrict__ bpre,
                                                   int* __restrict__ ptr, int N) {
  __shared__ int ts[256];
  int tid = threadIdx.x;
  int base = blockIdx.x * 1024 + tid * 4;
  int c0 = 0, c1 = 0, c2 = 0, c3 = 0;
  if (base + 0 < N) c0 = cnt[base + 0];
  if (base + 1 < N) c1 = cnt[base + 1];
  if (base + 2 < N) c2 = cnt[base + 2];
  if (base + 3 < N) c3 = cnt[base + 3];
  ts[tid] = c0 + c1 + c2 + c3;
  __syncthreads();
  for (int off = 1; off < 256; off <<= 1) {
    int v = ts[tid];
    if (tid >= off) v += ts[tid - off];
    __syncthreads();
    ts[tid] = v;
    __syncthreads();
  }
  int run = bpre[blockIdx.x] + (tid ? ts[tid - 1] : 0);
  if (base + 0 < N) { ptr[base + 0] = run; run += c0; }
  if (base + 1 < N) { ptr[base + 1] = run; run += c1; }
  if (base + 2 < N) { ptr[base + 2] = run; run += c2; }
  if (base + 3 < N) { ptr[base + 3] = run; run += c3; }
}

// atomic-free scatter: slot = ptr[col] + xcd_base + local_rank
__global__ void edge_scatter(const int* __restrict__ ei, const void* __restrict__ ea,
                             const int* __restrict__ flags,
                             const float* __restrict__ dis,
                             const int* __restrict__ ptr,
                             const unsigned short* __restrict__ xb,
                             const int* __restrict__ rank,
                             int2* __restrict__ epair, int E) {
  int e = blockIdx.x * blockDim.x + threadIdx.x;
  if (e >= E) return;
  int is64 = flags[1], isf32 = flags[0];
  int r = is64 ? ei[2 * e] : ei[e];
  int c = is64 ? ei[2 * (E + e)] : ei[E + e];
  float w = isf32 ? ((const float*)ea)[e] : u2f(((const unsigned short*)ea)[e]);
  float nrm = dis[r] * w * dis[c];
  int rk = rank[e];
  int idx = ptr[c] + (int)xb[(size_t)c * 8 + (rk >> 20)] + (rk & 0xFFFFF);
  int2 pr; pr.x = r; pr.y = __float_as_int(nrm);
  epair[idx] = pr;
}

// ---------------- MFMA GEMM ----------------
template<int KC, int NT>
__global__ __launch_bounds__(256) void gemm_mfma(const unsigned short* __restrict__ Abf,
                                                 const unsigned short* __restrict__ Wswz,
                                                 unsigned short* __restrict__ H,
                                                 int M) {
  int wid = threadIdx.x >> 6, lane = threadIdx.x & 63;
  int row0 = (blockIdx.x * 4 + wid) * 16;
  if (row0 >= M) return;
  constexpr int K = KC * 32;
  constexpr int NC = NT * 16;
  f32x4 acc[NT];
#pragma unroll
  for (int t = 0; t < NT; ++t) acc[t] = {0.f, 0.f, 0.f, 0.f};
  size_t arow = (size_t)(row0 + (lane & 15)) * K + (lane >> 4) * 8;
#pragma unroll
  for (int kc = 0; kc < KC; ++kc) {
    short8 a = *(const short8*)&Abf[arow + kc * 32];
#pragma unroll
    for (int t = 0; t < NT; ++t) {
      short8 b = *(const short8*)&Wswz[((kc * NT + t) * 64 + lane) * 8];
      acc[t] = __builtin_amdgcn_mfma_f32_16x16x32_bf16(a, b, acc[t], 0, 0, 0);
    }
  }
  int orow = row0 + (lane >> 4) * 4;
  int ocol = lane & 15;
#pragma unroll
  for (int t = 0; t < NT; ++t)
#pragma unroll
    for (int r = 0; r < 4; ++r)
      H[(size_t)(orow + r) * NC + t * 16 + ocol] = f2us(acc[t][r]);
}

// ---------------- aggregations ----------------
// conv1: full wave per node; lane owns uint 'lane' (2 of 128 feats).
// Edge list consumed via coalesced lane-loads + uniform readlane broadcast.
__global__ __launch_bounds__(256) void agg_mish128(const unsigned* __restrict__ hu,
                                                   const float* __restrict__ dis,
                                                   const int* __restrict__ ptr,
                                                   const int2* __restrict__ ep,
                                                   const bf16* __restrict__ bias,
                                                   unsigned* __restrict__ g, int N) {
  int w = threadIdx.x >> 6, lane = threadIdx.x & 63;
  int n = blockIdx.x * 4 + w;
  float dn = dis[n];
  float self = dn * dn;
  unsigned u = hu[(size_t)n * 64 + lane];
  float acc0 = lo16(u) * self;
  float acc1 = hi16(u) * self;
  int e0 = ptr[n], e1 = ptr[n + 1];
  for (int base = e0; base < e1; base += 64) {
    int2 myp = {0, 0};
    if (base + lane < e1) myp = ep[base + lane];
    int m = e1 - base; if (m > 64) m = 64;
    int j = 0;
    for (; j + 4 <= m; j += 4) {
      int r0 = __builtin_amdgcn_readlane(myp.x, j);
      int r1 = __builtin_amdgcn_readlane(myp.x, j + 1);
      int r2 = __builtin_amdgcn_readlane(myp.x, j + 2);
      int r3 = __builtin_amdgcn_readlane(myp.x, j + 3);
      unsigned u0 = hu[(size_t)r0 * 64 + lane];
      unsigned u1 = hu[(size_t)r1 * 64 + lane];
      unsigned u2 = hu[(size_t)r2 * 64 + lane];
      unsigned u3 = hu[(size_t)r3 * 64 + lane];
      float w0 = __uint_as_float(__builtin_amdgcn_readlane(myp.y, j));
      float w1 = __uint_as_float(__builtin_amdgcn_readlane(myp.y, j + 1));
      float w2 = __uint_as_float(__builtin_amdgcn_readlane(myp.y, j + 2));
      float w3 = __uint_as_float(__builtin_amdgcn_readlane(myp.y, j + 3));
      acc0 += lo16(u0) * w0; acc1 += hi16(u0) * w0;
      acc0 += lo16(u1) * w1; acc1 += hi16(u1) * w1;
      acc0 += lo16(u2) * w2; acc1 += hi16(u2) * w2;
      acc0 += lo16(u3) * w3; acc1 += hi16(u3) * w3;
    }
    for (; j < m; ++j) {
      int rr = __builtin_amdgcn_readlane(myp.x, j);
      float ww = __uint_as_float(__builtin_amdgcn_readlane(myp.y, j));
      unsigned uu = hu[(size_t)rr * 64 + lane];
      acc0 += lo16(uu) * ww;
      acc1 += hi16(uu) * ww;
    }
  }
  unsigned bb = ((const unsigned*)bias)[lane];
  float m0 = mishf(acc0 + lo16(bb));
  float m1 = mishf(acc1 + hi16(bb));
  g[(size_t)n * 64 + lane] = ((unsigned)f2us(m1) << 16) | f2us(m0);
}

// conv2 + readout: full wave per node; lane owns ONE of 64 feats (ushort).
// Value-split butterfly reduces the 8 readout dots in 10 shfl.
__global__ __launch_bounds__(256) void agg_mish64_ro(const unsigned short* __restrict__ hus,
                                                     const float* __restrict__ dis,
                                                     const int* __restrict__ ptr,
                                                     const int2* __restrict__ ep,
                                                     const bf16* __restrict__ bias,
                                                     const bf16* __restrict__ Wro,
                                                     const bf16* __restrict__ bro,
                                                     float* __restrict__ out8, int N) {
  int w = threadIdx.x >> 6, lane = threadIdx.x & 63;
  int n = blockIdx.x * 4 + w;
  float dn = dis[n];
  float self = dn * dn;
  float acc = u2f(hus[(size_t)n * 64 + lane]) * self;
  int e0 = ptr[n], e1 = ptr[n + 1];
  for (int base = e0; base < e1; base += 64) {
    int2 myp = {0, 0};
    if (base + lane < e1) myp = ep[base + lane];
    int m = e1 - base; if (m > 64) m = 64;
    int j = 0;
    for (; j + 4 <= m; j += 4) {
      int r0 = __builtin_amdgcn_readlane(myp.x, j);
      int r1 = __builtin_amdgcn_readlane(myp.x, j + 1);
      int r2 = __builtin_amdgcn_readlane(myp.x, j + 2);
      int r3 = __builtin_amdgcn_readlane(myp.x, j + 3);
      float v0 = u2f(hus[(size_t)r0 * 64 + lane]);
      float v1 = u2f(hus[(size_t)r1 * 64 + lane]);
      float v2 = u2f(hus[(size_t)r2 * 64 + lane]);
      float v3 = u2f(hus[(size_t)r3 * 64 + lane]);
      float w0 = __uint_as_float(__builtin_amdgcn_readlane(myp.y, j));
      float w1 = __uint_as_float(__builtin_amdgcn_readlane(myp.y, j + 1));
      float w2 = __uint_as_float(__builtin_amdgcn_readlane(myp.y, j + 2));
      float w3 = __uint_as_float(__builtin_amdgcn_readlane(myp.y, j + 3));
      acc += v0 * w0 + v1 * w1 + v2 * w2 + v3 * w3;
    }
    for (; j < m; ++j) {
      int rr = __builtin_amdgcn_readlane(myp.x, j);
      float ww = __uint_as_float(__builtin_amdgcn_readlane(myp.y, j));
      acc += u2f(hus[(size_t)rr * 64 + lane]) * ww;
    }
  }
  float mv = mishf(acc + u2f(((const unsigned short*)bias)[lane]));
  // readout partials: lane f holds row f of Wro[64][8]
  uint4 wr = ((const uint4*)Wro)[lane];
  float p0 = mv * lo16(wr.x), p1 = mv * hi16(wr.x);
  float p2 = mv * lo16(wr.y), p3 = mv * hi16(wr.y);
  float p4 = mv * lo16(wr.z), p5 = mv * hi16(wr.z);
  float p6 = mv * lo16(wr.w), p7 = mv * hi16(wr.w);
  // value-split reduce: 8 values over 64 lanes
  bool b0 = lane & 1;
  float q0 = (b0 ? p4 : p0) + __shfl_xor(b0 ? p0 : p4, 1);
  float q1 = (b0 ? p5 : p1) + __shfl_xor(b0 ? p1 : p5, 1);
  float q2 = (b0 ? p6 : p2) + __shfl_xor(b0 ? p2 : p6, 1);
  float q3 = (b0 ? p7 : p3) + __shfl_xor(b0 ? p3 : p7, 1);
  bool b1 = lane & 2;
  float r0 = (b1 ? q2 : q0) + __shfl_xor(b1 ? q0 : q2, 2);
  float r1 = (b1 ? q3 : q1) + __shfl_xor(b1 ? q1 : q3, 2);
  bool b2v = lane & 4;
  float t = (b2v ? r1 : r0) + __shfl_xor(b2v ? r0 : r1, 4);
  t += __shfl_xor(t, 8);
  t += __shfl_xor(t, 16);
  t += __shfl_xor(t, 32);
  if (lane < 8) {
    int oidx = ((lane & 1) << 2) | (lane & 2) | ((lane >> 2) & 1);
    out8[(size_t)n * 8 + oidx] = mishf(t + u2f(((const unsigned short*)bro)[oidx]));
  }
}

// ---------------- dense tail ----------------

__global__ __launch_bounds__(256) void fc1_kernel(const float* __restrict__ feat,
                                                  const bf16* __restrict__ W,
                                                  const bf16* __restrict__ bias,
                                                  float* __restrict__ z) {
  __shared__ float fr[1600];
  int b = blockIdx.x, tid = threadIdx.x;
  for (int i = tid; i < 1600; i += 256) fr[i] = feat[(size_t)b * 1600 + i];
  __syncthreads();
  if (tid < NROI) {
    float acc = b2f(bias[tid]);
#pragma unroll 8
    for (int k = 0; k < 1600; ++k) acc += fr[k] * b2f(W[k * NROI + tid]);
    z[b * NROI + tid] = acc;
  }
}

__global__ __launch_bounds__(256) void bn_stats(const float* __restrict__ z,
                                                float* mu, float* rvar, int B) {
  int j = blockIdx.x;
  int tid = threadIdx.x;
  float v = z[tid * NROI + j];
  float s = v, q = v * v;
  for (int off = 32; off > 0; off >>= 1) {
    s += __shfl_down(s, off);
    q += __shfl_down(q, off);
  }
  __shared__ float ss[4], qq[4];
  int w = tid >> 6, lane = tid & 63;
  if (lane == 0) { ss[w] = s; qq[w] = q; }
  __syncthreads();
  if (tid == 0) {
    float S = ss[0] + ss[1] + ss[2] + ss[3];
    float Q = qq[0] + qq[1] + qq[2] + qq[3];
    float m = S / (float)B;
    float var = Q / (float)B - m * m;
    mu[j] = m;
    rvar[j] = rsqrtf(var + 1e-5f);
  }
}

__global__ __launch_bounds__(256) void head_kernel(const float* __restrict__ z,
                                                   const float* __restrict__ mu,
                                                   const float* __restrict__ rvar,
                                                   const bf16* __restrict__ gamma,
                                                   const bf16* __restrict__ beta,
                                                   const bf16* __restrict__ Wfc2,
                                                   const bf16* __restrict__ bfc2,
                                                   const bf16* __restrict__ Wd1,
                                                   const bf16* __restrict__ bd1,
                                                   const bf16* __restrict__ Wd2,
                                                   const bf16* __restrict__ bd2,
                                                   float* __restrict__ out, int B) {
  __shared__ float mid[NROI];
  __shared__ float t[64];
  int b = blockIdx.x, tid = threadIdx.x;
  if (tid < NROI) {
    float v = (z[b * NROI + tid] - mu[tid]) * rvar[tid] * b2f(gamma[tid]) + b2f(beta[tid]);
    mid[tid] = mishf(v);
  }
  __syncthreads();
  if (tid < 64) {
    float acc = b2f(bd1[tid]);
#pragma unroll 8
    for (int j = 0; j < NROI; ++j) acc += mid[j] * b2f(Wd1[j * 64 + tid]);
    t[tid] = fmaxf(acc, 0.0f);
  }
  if (tid >= 64 && tid < 66) {
    int c = tid - 64;
    float acc = b2f(bfc2[c]);
    for (int j = 0; j < NROI; ++j) acc += mid[j] * b2f(Wfc2[j * 2 + c]);
    out[b * 2 + c] = acc;
  }
  __syncthreads();
  if (tid < 6) {
    float acc = b2f(bd2[tid]);
#pragma unroll 8
    for (int k = 0; k < 64; ++k) acc += t[k] * b2f(Wd2[k * 6 + tid]);
    out[B * 2 + b * 6 + tid] = acc;
  }
}

// ---------------- launch ----------------

extern "C" void kernel_launch(void* const* d_in, const int* in_sizes, int n_in,
                              void* d_out, int out_size, void* d_ws, size_t ws_size,
                              hipStream_t stream) {
  const void* x  = d_in[0];
  const int*  ei = (const int*)d_in[1];
  const void* ea = d_in[2];
  float* out = (float*)d_out;

  int N = in_sizes[0] / NROI;   // 51200
  int E = in_sizes[2];          // 1638400
  int B = N / NROI;             // 256

  char* p = (char*)d_ws;
  auto carve = [&](size_t bytes) -> void* {
    void* r = (void*)p;
    p += (bytes + 255) & ~(size_t)255;
    return r;
  };
  int*   flags = (int*)carve(16);
  bf16*  cw    = (bf16*)carve(400000 * 2);
  float* dis   = (float*)carve((size_t)N * 4);
  unsigned long long* dc8 = (unsigned long long*)carve((size_t)8 * N * 8);
  int*   cnt   = (int*)carve((size_t)N * 4);
  unsigned short* xbse = (unsigned short*)carve((size_t)N * 8 * 2);
  int*   ptr   = (int*)carve(((size_t)N + 1) * 4);
  int*   bsum  = (int*)carve(1024);
  int*   bpre  = (int*)carve(1024);
  int2*  epair = (int2*)carve((size_t)E * 8);
  unsigned short* h = (unsigned short*)carve((size_t)N * 128 * 2);
  // union region: rank[E] (dead after edge_scatter) / xbf[N][224] (dead after
  // gemm1) / g[N][128] bf16 — disjoint stream-ordered lifetimes.
  size_t xg_bytes = (size_t)N * 224 * 2;
  size_t rk_bytes = (size_t)E * 4;
  char* xg = (char*)carve(xg_bytes > rk_bytes ? xg_bytes : rk_bytes);
  int* rank = (int*)xg;
  unsigned short* xbf = (unsigned short*)xg;
  unsigned* g = (unsigned*)xg;
  unsigned short* w1swz = (unsigned short*)carve(7 * 8 * 512 * 2);
  unsigned short* w2swz = (unsigned short*)carve(4 * 4 * 512 * 2);
  float* out8  = (float*)carve((size_t)N * 8 * 4);
  float* z     = (float*)carve((size_t)B * NROI * 4);
  float* mu    = (float*)carve(NROI * 4);
  float* rv    = (float*)carve(NROI * 4);

  WArgs wa;
  int run = 0;
  int maxn = 0;
  for (int t = 0; t < 16; ++t) {
    wa.src[t] = d_in[3 + t];
    wa.n[t]   = in_sizes[3 + t];
    wa.off[t] = run;
    run += in_sizes[3 + t];
    if (in_sizes[3 + t] > maxn) maxn = in_sizes[3 + t];
  }
  const bf16* W1   = cw + wa.off[0];
  const bf16* b1   = cw + wa.off[1];
  const bf16* W2   = cw + wa.off[2];
  const bf16* b2   = cw + wa.off[3];
  const bf16* Wro  = cw + wa.off[4];
  const bf16* bro  = cw + wa.off[5];
  const bf16* Wfc1 = cw + wa.off[6];
  const bf16* bfc1 = cw + wa.off[7];
  const bf16* gam  = cw + wa.off[8];
  const bf16* bet  = cw + wa.off[9];
  const bf16* Wfc2 = cw + wa.off[10];
  const bf16* bfc2 = cw + wa.off[11];
  const bf16* Wd1  = cw + wa.off[12];
  const bf16* bd1  = cw + wa.off[13];
  const bf16* Wd2  = cw + wa.off[14];
  const bf16* bd2  = cw + wa.off[15];

  int nb = (N + 255) / 256;
  int eb = (E + 255) / 256;
  int nscan = (N + 1023) / 1024;

  detect_kernel<<<1, 256, 0, stream>>>((const unsigned short*)x,
                                       (const unsigned*)ei, flags);
  dim3 wg((maxn + 255) / 256, 16);
  convert_weights<<<wg, 256, 0, stream>>>(wa, cw, flags);
  swizzleW<<<(7 * 8 * 512 + 255) / 256, 256, 0, stream>>>(
      (const unsigned short*)W1, w1swz, 200, 7, 8);
  swizzleW<<<(4 * 4 * 512 + 255) / 256, 256, 0, stream>>>(
      (const unsigned short*)W2, w2swz, 128, 4, 4);

  long long dctot = (long long)8 * N;
  init_dc8<<<(int)((dctot + 255) / 256), 256, 0, stream>>>(dc8, dctot);
  edge_count<<<eb, 256, 0, stream>>>(ei, ea, flags, dc8, rank, N, E);
  xcd_base<<<nb, 256, 0, stream>>>(dc8, dis, cnt, xbse, N);
  scan_phase1<<<nscan, 256, 0, stream>>>(cnt, bsum, N);
  scan_phase2<<<1, 64, 0, stream>>>(bsum, bpre, ptr, nscan, N);
  scan_phase3<<<nscan, 256, 0, stream>>>(cnt, bpre, ptr, N);
  edge_scatter<<<eb, 256, 0, stream>>>(ei, ea, flags, dis, ptr, xbse, rank,
                                       epair, E);

  long long xtot = (long long)N * 224;
  xbf_convert<<<(int)((xtot + 255) / 256), 256, 0, stream>>>(x, xbf, flags, N);
  gemm_mfma<7, 8><<<N / 64, 256, 0, stream>>>(xbf, w1swz, h, N);
  agg_mish128<<<N / 4, 256, 0, stream>>>((const unsigned*)h, dis, ptr, epair,
                                         b1, g, N);
  gemm_mfma<4, 4><<<N / 64, 256, 0, stream>>>((const unsigned short*)g, w2swz, h, N);
  agg_mish64_ro<<<N / 4, 256, 0, stream>>>(h, dis, ptr, epair, b2, Wro, bro,
                                           out8, N);

  fc1_kernel<<<B, 256, 0, stream>>>(out8, Wfc1, bfc1, z);
  bn_stats<<<NROI, 256, 0, stream>>>(z, mu, rv, B);
  head_kernel<<<B, 256, 0, stream>>>(z, mu, rv, gam, bet, Wfc2, bfc2,
                                     Wd1, bd1, Wd2, bd2, out, B);
}